// Round 1
// baseline (1866.072 us; speedup 1.0000x reference)
//
#include <hip/hip_runtime.h>

#define NN 100000
#define NE 1200000
#define DIN 7
#define DD 64
#define NL 3
#define NG 64
#define PCH 16
#define NCHUNK (NN / PCH)  // 6250

// ---------------- node embed: x_emb = relu(x @ Wn) ----------------
__global__ __launch_bounds__(256) void k_embed_node(const float* __restrict__ x,
        const float* __restrict__ Wn, float* __restrict__ x_emb) {
    __shared__ float sW[DIN * DD];
    int t = threadIdx.x;
    for (int i = t; i < DIN * DD; i += 256) sW[i] = Wn[i];
    __syncthreads();
    int gid = blockIdx.x * 256 + t;          // exact grid: NN*DD/256
    int n = gid >> 6, d = gid & 63;
    const float* xr = x + n * DIN;
    float a = 0.f;
#pragma unroll
    for (int k = 0; k < DIN; ++k) a += xr[k] * sW[k * DD + d];
    x_emb[gid] = fmaxf(a, 0.f);
}

// ------------- edge embed: acc[row] += relu([ea, x[col]] @ Wne); counts -------------
__global__ __launch_bounds__(256) void k_edge_embed(const int* __restrict__ ei,
        const float* __restrict__ ea, const float* __restrict__ x,
        const float* __restrict__ Wne, float* __restrict__ acc,
        float* __restrict__ cnt_row, float* __restrict__ deg) {
    __shared__ float sW[8 * 63];
    int t = threadIdx.x;
    for (int i = t; i < 8 * 63; i += 256) sW[i] = Wne[i];
    __syncthreads();
    int gid = blockIdx.x * 256 + t;          // exact grid: NE*DD/256 (76.8M < 2^31)
    int e = gid >> 6, d = gid & 63;
    int row = ei[e], col = ei[NE + e];
    if (d == 63) {
        atomicAdd(&cnt_row[row], 1.f);
        atomicAdd(&deg[col], 1.f);
        return;
    }
    const float* xr = x + col * DIN;
    float v = ea[e] * sW[d];                 // Wne row 0 multiplies edge_attr
#pragma unroll
    for (int k = 0; k < DIN; ++k) v += xr[k] * sW[(k + 1) * 63 + d];
    v = fmaxf(v, 0.f);
    atomicAdd(&acc[row * DD + d], v);
}

// ------- x_agg_emb = relu([mean(node_edge), deg] @ Wa), block = 4 nodes -------
__global__ __launch_bounds__(256) void k_agg_embed(const float* __restrict__ acc,
        const float* __restrict__ cnt_row, const float* __restrict__ deg,
        const float* __restrict__ Wa, float* __restrict__ x_agg_emb) {
    __shared__ float sW[DD * DD];
    __shared__ float sin_[4][DD];
    int t = threadIdx.x;
    for (int i = t; i < DD * DD; i += 256) sW[i] = Wa[i];
    int nl = t >> 6, d = t & 63;
    int n = blockIdx.x * 4 + nl;             // exact: NN/4 blocks
    float c = fmaxf(cnt_row[n], 1.f);
    sin_[nl][d] = (d < 63) ? acc[n * DD + d] / c : deg[n];
    __syncthreads();
    float o = 0.f;
#pragma unroll 8
    for (int k = 0; k < DD; ++k) o += sin_[nl][k] * sW[k * DD + d];
    x_agg_emb[n * DD + d] = fmaxf(o, 0.f);
}

// ---------- message scatter: acc[row*64+d] += ea[e] * x_emb[col*64+d] ----------
__global__ __launch_bounds__(256) void k_msg_scatter(const int* __restrict__ ei,
        const float* __restrict__ ea, const float* __restrict__ x_emb,
        float* __restrict__ acc) {
    int gid = blockIdx.x * 256 + threadIdx.x;  // exact grid
    int e = gid >> 6, d = gid & 63;
    int row = ei[e], col = ei[NE + e];
    float v = ea[e] * x_emb[col * DD + d];
    atomicAdd(&acc[row * DD + d], v);
}

// ---------- node update: m = relu([x_agg, x_agg_emb]@Wm); x_emb = relu([x_emb, m]@Wu) ----------
__global__ __launch_bounds__(256) void k_node_update(const float* __restrict__ acc,
        const float* __restrict__ cnt_row, const float* __restrict__ x_agg_emb,
        const float* __restrict__ Wm, const float* __restrict__ Wu,
        float* __restrict__ x_emb) {
    __shared__ float sWm[2 * DD * DD];       // 32 KB
    __shared__ float sin_[4][2 * DD];
    __shared__ float sxe[4][DD];
    __shared__ float sm[4][DD];
    int t = threadIdx.x;
    for (int i = t; i < 2 * DD * DD; i += 256) sWm[i] = Wm[i];
    int nl = t >> 6, d = t & 63;
    int n = blockIdx.x * 4 + nl;             // exact: NN/4 = 25000 blocks
    float c = fmaxf(cnt_row[n], 1.f);
    sin_[nl][d]      = acc[n * DD + d] / c;
    sin_[nl][DD + d] = x_agg_emb[n * DD + d];
    sxe[nl][d]       = x_emb[n * DD + d];
    __syncthreads();
    float m = 0.f;
#pragma unroll 8
    for (int k = 0; k < 2 * DD; ++k) m += sin_[nl][k] * sWm[k * DD + d];
    m = fmaxf(m, 0.f);
    sm[nl][d] = m;
    __syncthreads();
    float o = 0.f;
#pragma unroll 8
    for (int k = 0; k < DD; ++k) o += sxe[nl][k] * Wu[k * DD + d];
#pragma unroll 8
    for (int k = 0; k < DD; ++k) o += sm[nl][k] * Wu[(DD + k) * DD + d];
    x_emb[n * DD + d] = fmaxf(o, 0.f);       // in-place safe: inputs staged in LDS
}

// ---------- graph pool: chunked scatter over sorted batch ----------
__global__ __launch_bounds__(256) void k_pool(const float* __restrict__ x_emb,
        const int* __restrict__ batch, float* __restrict__ g_sum,
        float* __restrict__ g_cnt) {
    int gid = blockIdx.x * 256 + threadIdx.x;
    int chunk = gid >> 6, d = gid & 63;
    if (chunk >= NCHUNK) return;
    int n0 = chunk * PCH;
    int curb = batch[n0];
    float s = 0.f, c = 0.f;
    for (int n = n0; n < n0 + PCH; ++n) {
        int b = batch[n];
        if (b != curb) {
            atomicAdd(&g_sum[curb * DD + d], s);
            if (d == 0) atomicAdd(&g_cnt[curb], c);
            s = 0.f; c = 0.f; curb = b;
        }
        s += x_emb[n * DD + d];
        c += 1.f;
    }
    atomicAdd(&g_sum[curb * DD + d], s);
    if (d == 0) atomicAdd(&g_cnt[curb], c);
}

// ---------- g = relu(mean_pool @ Wg) ----------
__global__ __launch_bounds__(256) void k_graph(const float* __restrict__ g_sum,
        const float* __restrict__ g_cnt, const float* __restrict__ Wg,
        float* __restrict__ g) {
    int gid = blockIdx.x * 256 + threadIdx.x;  // exact: NG*DD/256 = 16 blocks
    int gi = gid >> 6, d = gid & 63;
    float c = fmaxf(g_cnt[gi], 1.f);
    float o = 0.f;
#pragma unroll 8
    for (int k = 0; k < DD; ++k) o += (g_sum[gi * DD + k] / c) * Wg[k * DD + d];
    g[gid] = fmaxf(o, 0.f);
}

// ---------- readout: q[n] = [g[batch[n]], x_emb[n]] @ Wr + b ----------
__global__ __launch_bounds__(256) void k_readout(const float* __restrict__ x_emb,
        const float* __restrict__ g, const int* __restrict__ batch,
        const float* __restrict__ Wr, const float* __restrict__ br,
        float* __restrict__ q) {
    __shared__ float sWr[2 * DD];
    int t = threadIdx.x;
    if (t < 2 * DD) sWr[t] = Wr[t];
    __syncthreads();
    int n = blockIdx.x * 256 + t;
    if (n >= NN) return;
    int b = batch[n];
    const float* gr = g + b * DD;
    const float* xr = x_emb + n * DD;
    float o = br[0];
#pragma unroll 8
    for (int k = 0; k < DD; ++k) o += gr[k] * sWr[k];
#pragma unroll 8
    for (int k = 0; k < DD; ++k) o += xr[k] * sWr[DD + k];
    q[n] = o;
}

extern "C" void kernel_launch(void* const* d_in, const int* in_sizes, int n_in,
                              void* d_out, int out_size, void* d_ws, size_t ws_size,
                              hipStream_t stream) {
    const float* x   = (const float*)d_in[0];
    const int*   ei  = (const int*)d_in[1];
    const float* ea  = (const float*)d_in[2];
    const int*   bat = (const int*)d_in[3];
    const float* Wn  = (const float*)d_in[4];
    const float* Wne = (const float*)d_in[5];
    const float* Wa  = (const float*)d_in[6];
    const float* Wm  = (const float*)d_in[7];
    const float* Wu  = (const float*)d_in[8];
    const float* Wg  = (const float*)d_in[9];
    const float* Wr  = (const float*)d_in[10];
    const float* br  = (const float*)d_in[11];
    float* q = (float*)d_out;

    float* ws        = (float*)d_ws;
    float* x_emb     = ws;                         // NN*DD
    float* acc       = x_emb + (size_t)NN * DD;    // NN*DD
    float* x_agg_emb = acc + (size_t)NN * DD;      // NN*DD
    float* cnt_row   = x_agg_emb + (size_t)NN * DD;// NN
    float* deg       = cnt_row + NN;               // NN
    float* g_sum     = deg + NN;                   // NG*DD
    float* g_cnt     = g_sum + NG * DD;            // NG
    float* g         = g_cnt + NG;                 // NG*DD

    // zero accumulators (cnt_row, deg, g_sum, g_cnt are contiguous)
    hipMemsetAsync(acc, 0, (size_t)NN * DD * sizeof(float), stream);
    hipMemsetAsync(cnt_row, 0, (size_t)(2 * NN + NG * DD + NG) * sizeof(float), stream);

    k_embed_node<<<NN * DD / 256, 256, 0, stream>>>(x, Wn, x_emb);
    k_edge_embed<<<NE / 4, 256, 0, stream>>>(ei, ea, x, Wne, acc, cnt_row, deg);
    k_agg_embed<<<NN / 4, 256, 0, stream>>>(acc, cnt_row, deg, Wa, x_agg_emb);

    for (int l = 0; l < NL; ++l) {
        hipMemsetAsync(acc, 0, (size_t)NN * DD * sizeof(float), stream);
        k_msg_scatter<<<NE / 4, 256, 0, stream>>>(ei, ea, x_emb, acc);
        k_node_update<<<NN / 4, 256, 0, stream>>>(acc, cnt_row, x_agg_emb,
            Wm + (size_t)l * 2 * DD * DD, Wu + (size_t)l * 2 * DD * DD, x_emb);
    }

    k_pool<<<(NCHUNK * DD + 255) / 256, 256, 0, stream>>>(x_emb, bat, g_sum, g_cnt);
    k_graph<<<NG * DD / 256, 256, 0, stream>>>(g_sum, g_cnt, Wg, g);
    k_readout<<<(NN + 255) / 256, 256, 0, stream>>>(x_emb, g, bat, Wr, br, q);
}

// Round 2
// 1213.629 us; speedup vs baseline: 1.5376x; 1.5376x over previous
//
#include <hip/hip_runtime.h>

#define NN 100000
#define NE 1200000
#define DIN 7
#define DD 64
#define NL 3
#define NG 64
#define PCH 16
#define NCHUNK (NN / PCH)   // 6250
#define NSB 391             // ceil(NN/256) scan blocks

// ---------------- node embed: x_emb = relu(x @ Wn) ----------------
__global__ __launch_bounds__(256) void k_embed_node(const float* __restrict__ x,
        const float* __restrict__ Wn, float* __restrict__ x_emb) {
    __shared__ float sW[DIN * DD];
    int t = threadIdx.x;
    for (int i = t; i < DIN * DD; i += 256) sW[i] = Wn[i];
    __syncthreads();
    int gid = blockIdx.x * 256 + t;          // exact grid: NN*DD/256
    int n = gid >> 6, d = gid & 63;
    const float* xr = x + n * DIN;
    float a = 0.f;
#pragma unroll
    for (int k = 0; k < DIN; ++k) a += xr[k] * sW[k * DD + d];
    x_emb[gid] = fmaxf(a, 0.f);
}

// ---------------- CSR build ----------------
__global__ __launch_bounds__(256) void k_hist(const int* __restrict__ ei,
        int* __restrict__ cnti, int* __restrict__ degi) {
    int e = blockIdx.x * 256 + threadIdx.x;
    if (e >= NE) return;
    atomicAdd(&cnti[ei[e]], 1);          // out-count by row
    atomicAdd(&degi[ei[NE + e]], 1);     // in-degree by col
}

__global__ __launch_bounds__(256) void k_scan1(const int* __restrict__ cnti,
        int* __restrict__ rowptr, int* __restrict__ bsum) {
    __shared__ int s[256];
    int t = threadIdx.x, i = blockIdx.x * 256 + t;
    int v = (i < NN) ? cnti[i] : 0;
    s[t] = v; __syncthreads();
    for (int off = 1; off < 256; off <<= 1) {
        int u = (t >= off) ? s[t - off] : 0; __syncthreads();
        s[t] += u; __syncthreads();
    }
    if (i < NN) rowptr[i] = s[t] - v;     // exclusive within block
    if (t == 255) bsum[blockIdx.x] = s[255];
}

__global__ __launch_bounds__(512) void k_scan2(const int* __restrict__ bsum,
        int* __restrict__ boff) {
    __shared__ int s[512];
    int t = threadIdx.x;
    int v = (t < NSB) ? bsum[t] : 0;
    s[t] = v; __syncthreads();
    for (int off = 1; off < 512; off <<= 1) {
        int u = (t >= off) ? s[t - off] : 0; __syncthreads();
        s[t] += u; __syncthreads();
    }
    boff[t] = s[t] - v;                    // exclusive
}

__global__ __launch_bounds__(256) void k_scan3(int* __restrict__ rowptr,
        const int* __restrict__ boff) {
    int i = blockIdx.x * 256 + threadIdx.x;
    if (i < NN) rowptr[i] += boff[i >> 8];
    if (i == 0) rowptr[NN] = NE;
}

__global__ __launch_bounds__(256) void k_reorder(const int* __restrict__ ei,
        const float* __restrict__ ea, const int* __restrict__ rowptr,
        int* __restrict__ tmp, int* __restrict__ ecol, float* __restrict__ eat) {
    int e = blockIdx.x * 256 + threadIdx.x;
    if (e >= NE) return;
    int row = ei[e];
    int p = rowptr[row] + atomicAdd(&tmp[row], 1);
    ecol[p] = ei[NE + e];
    eat[p] = ea[e];
}

// ------- fused: node_edge mean (gather) + deg -> x_agg_emb = relu(.@Wa) -------
__global__ __launch_bounds__(256) void k_edge_agg(const float* __restrict__ x,
        const int* __restrict__ rowptr, const int* __restrict__ ecol,
        const float* __restrict__ eat, const int* __restrict__ degi,
        const float* __restrict__ Wne, const float* __restrict__ Wa,
        float* __restrict__ C) {
    __shared__ float sWne[8 * 63];
    __shared__ float sWa[DD * DD];
    __shared__ float sin_[4][DD];
    int t = threadIdx.x;
    for (int i = t; i < 8 * 63; i += 256) sWne[i] = Wne[i];
    for (int i = t; i < DD * DD; i += 256) sWa[i] = Wa[i];
    __syncthreads();
    int wid = t >> 6, lane = t & 63;
    int n = blockIdx.x * 4 + wid;            // exact: NN/4 blocks
    int s0 = rowptr[n], s1 = rowptr[n + 1];
    int dl = (lane < 63) ? lane : 0;         // avoid OOB for lane 63
    float acc = 0.f;
    for (int base = s0; base < s1; base += 64) {
        int m = min(64, s1 - base);
        int cc = (lane < m) ? ecol[base + lane] : 0;
        float aa = (lane < m) ? eat[base + lane] : 0.f;
        for (int j = 0; j < m; ++j) {
            int c = __shfl(cc, j);
            float a = __shfl(aa, j);
            float xv = (lane < DIN) ? x[c * DIN + lane] : 0.f;
            float v = a * sWne[dl];
#pragma unroll
            for (int k = 0; k < DIN; ++k) v += __shfl(xv, k) * sWne[(k + 1) * 63 + dl];
            if (lane < 63) acc += fmaxf(v, 0.f);
        }
    }
    float cval = (float)(s1 - s0);
    float mean = acc / fmaxf(cval, 1.f);
    sin_[wid][lane] = (lane < 63) ? mean : (float)degi[n];
    __syncthreads();
    float o = 0.f;
#pragma unroll 8
    for (int k = 0; k < DD; ++k) o += sin_[wid][k] * sWa[k * DD + lane];
    C[n * DD + lane] = fmaxf(o, 0.f);
}

// ------- fused per layer: x_agg = seg_mean(ea * xsrc[col]) (gather);
//         m = relu([x_agg, C]@Wm); xdst = relu([xsrc, m]@Wu) -------
__global__ __launch_bounds__(256) void k_msg_update(const int* __restrict__ rowptr,
        const int* __restrict__ ecol, const float* __restrict__ eat,
        const float* __restrict__ xsrc, const float* __restrict__ C,
        const float* __restrict__ Wm, const float* __restrict__ Wu,
        float* __restrict__ xdst) {
    __shared__ float sWm[2 * DD * DD];       // 32 KB
    __shared__ float sin_[4][2 * DD];
    __shared__ float sxe[4][DD];
    __shared__ float sm[4][DD];
    int t = threadIdx.x;
    for (int i = t; i < 2 * DD * DD; i += 256) sWm[i] = Wm[i];  // completes by sync below
    int wid = t >> 6, lane = t & 63;
    int n = blockIdx.x * 4 + wid;            // exact: NN/4 = 25000 blocks
    int s0 = rowptr[n], s1 = rowptr[n + 1];
    float acc = 0.f;
    for (int base = s0; base < s1; base += 64) {
        int m = min(64, s1 - base);
        int cc = (lane < m) ? ecol[base + lane] : 0;
        float aa = (lane < m) ? eat[base + lane] : 0.f;
        int j = 0;
        for (; j + 4 <= m; j += 4) {         // 4-deep pipelined gather
            int c0 = __shfl(cc, j), c1 = __shfl(cc, j + 1);
            int c2 = __shfl(cc, j + 2), c3 = __shfl(cc, j + 3);
            float a0 = __shfl(aa, j), a1 = __shfl(aa, j + 1);
            float a2 = __shfl(aa, j + 2), a3 = __shfl(aa, j + 3);
            float v0 = xsrc[c0 * DD + lane], v1 = xsrc[c1 * DD + lane];
            float v2 = xsrc[c2 * DD + lane], v3 = xsrc[c3 * DD + lane];
            acc += a0 * v0; acc += a1 * v1; acc += a2 * v2; acc += a3 * v3;
        }
        for (; j < m; ++j) {
            int c = __shfl(cc, j);
            float a = __shfl(aa, j);
            acc += a * xsrc[c * DD + lane];
        }
    }
    float cval = (float)(s1 - s0);
    sin_[wid][lane] = acc / fmaxf(cval, 1.f);
    sin_[wid][DD + lane] = C[n * DD + lane];
    sxe[wid][lane] = xsrc[n * DD + lane];
    __syncthreads();
    float mm = 0.f;
#pragma unroll 8
    for (int k = 0; k < 2 * DD; ++k) mm += sin_[wid][k] * sWm[k * DD + lane];
    mm = fmaxf(mm, 0.f);
    sm[wid][lane] = mm;
    __syncthreads();
    float o = 0.f;
#pragma unroll 8
    for (int k = 0; k < DD; ++k) o += sxe[wid][k] * Wu[k * DD + lane];
#pragma unroll 8
    for (int k = 0; k < DD; ++k) o += sm[wid][k] * Wu[(DD + k) * DD + lane];
    xdst[n * DD + lane] = fmaxf(o, 0.f);
}

// ---------- graph pool: chunked scatter over sorted batch ----------
__global__ __launch_bounds__(256) void k_pool(const float* __restrict__ x_emb,
        const int* __restrict__ batch, float* __restrict__ g_sum,
        float* __restrict__ g_cnt) {
    int gid = blockIdx.x * 256 + threadIdx.x;
    int chunk = gid >> 6, d = gid & 63;
    if (chunk >= NCHUNK) return;
    int n0 = chunk * PCH;
    int curb = batch[n0];
    float s = 0.f, c = 0.f;
    for (int n = n0; n < n0 + PCH; ++n) {
        int b = batch[n];
        if (b != curb) {
            atomicAdd(&g_sum[curb * DD + d], s);
            if (d == 0) atomicAdd(&g_cnt[curb], c);
            s = 0.f; c = 0.f; curb = b;
        }
        s += x_emb[n * DD + d];
        c += 1.f;
    }
    atomicAdd(&g_sum[curb * DD + d], s);
    if (d == 0) atomicAdd(&g_cnt[curb], c);
}

__global__ __launch_bounds__(256) void k_graph(const float* __restrict__ g_sum,
        const float* __restrict__ g_cnt, const float* __restrict__ Wg,
        float* __restrict__ g) {
    int gid = blockIdx.x * 256 + threadIdx.x;  // exact: 16 blocks
    int gi = gid >> 6, d = gid & 63;
    float c = fmaxf(g_cnt[gi], 1.f);
    float o = 0.f;
#pragma unroll 8
    for (int k = 0; k < DD; ++k) o += (g_sum[gi * DD + k] / c) * Wg[k * DD + d];
    g[gid] = fmaxf(o, 0.f);
}

__global__ __launch_bounds__(256) void k_readout(const float* __restrict__ x_emb,
        const float* __restrict__ g, const int* __restrict__ batch,
        const float* __restrict__ Wr, const float* __restrict__ br,
        float* __restrict__ q) {
    __shared__ float sWr[2 * DD];
    int t = threadIdx.x;
    if (t < 2 * DD) sWr[t] = Wr[t];
    __syncthreads();
    int n = blockIdx.x * 256 + t;
    if (n >= NN) return;
    int b = batch[n];
    const float* gr = g + b * DD;
    const float* xr = x_emb + n * DD;
    float o = br[0];
#pragma unroll 8
    for (int k = 0; k < DD; ++k) o += gr[k] * sWr[k];
#pragma unroll 8
    for (int k = 0; k < DD; ++k) o += xr[k] * sWr[DD + k];
    q[n] = o;
}

extern "C" void kernel_launch(void* const* d_in, const int* in_sizes, int n_in,
                              void* d_out, int out_size, void* d_ws, size_t ws_size,
                              hipStream_t stream) {
    const float* x   = (const float*)d_in[0];
    const int*   ei  = (const int*)d_in[1];
    const float* ea  = (const float*)d_in[2];
    const int*   bat = (const int*)d_in[3];
    const float* Wn  = (const float*)d_in[4];
    const float* Wne = (const float*)d_in[5];
    const float* Wa  = (const float*)d_in[6];
    const float* Wm  = (const float*)d_in[7];
    const float* Wu  = (const float*)d_in[8];
    const float* Wg  = (const float*)d_in[9];
    const float* Wr  = (const float*)d_in[10];
    const float* br  = (const float*)d_in[11];
    float* q = (float*)d_out;

    // ---- workspace layout ----
    float* A     = (float*)d_ws;                  // NN*DD (x_emb ping)
    float* B     = A + (size_t)NN * DD;           // NN*DD (x_emb pong)
    float* C     = B + (size_t)NN * DD;           // NN*DD (x_agg_emb)
    float* eat   = C + (size_t)NN * DD;           // NE  (CSR edge_attr)
    float* g_sum = eat + NE;                      // NG*DD
    float* g_cnt = g_sum + NG * DD;               // NG
    float* g     = g_cnt + NG;                    // NG*DD
    int* cnti    = (int*)(g + NG * DD);           // NN
    int* degi    = cnti + NN;                     // NN
    int* tmp     = degi + NN;                     // NN
    int* rowptr  = tmp + NN;                      // NN+1
    int* bsum    = rowptr + NN + 1;               // 512
    int* boff    = bsum + 512;                    // 512
    int* ecol    = boff + 512;                    // NE (CSR col)

    hipMemsetAsync(cnti, 0, (size_t)3 * NN * sizeof(int), stream);        // cnti,degi,tmp
    hipMemsetAsync(g_sum, 0, (size_t)(NG * DD + NG) * sizeof(float), stream);

    const int EB = (NE + 255) / 256;
    k_hist<<<EB, 256, 0, stream>>>(ei, cnti, degi);
    k_scan1<<<NSB, 256, 0, stream>>>(cnti, rowptr, bsum);
    k_scan2<<<1, 512, 0, stream>>>(bsum, boff);
    k_scan3<<<NSB, 256, 0, stream>>>(rowptr, boff);
    k_reorder<<<EB, 256, 0, stream>>>(ei, ea, rowptr, tmp, ecol, eat);

    k_embed_node<<<NN * DD / 256, 256, 0, stream>>>(x, Wn, A);
    k_edge_agg<<<NN / 4, 256, 0, stream>>>(x, rowptr, ecol, eat, degi, Wne, Wa, C);

    for (int l = 0; l < NL; ++l) {
        const float* src = (l & 1) ? B : A;
        float* dst = (l & 1) ? A : B;
        k_msg_update<<<NN / 4, 256, 0, stream>>>(rowptr, ecol, eat, src, C,
            Wm + (size_t)l * 2 * DD * DD, Wu + (size_t)l * 2 * DD * DD, dst);
    }
    // after L=3 layers result is in B

    k_pool<<<(NCHUNK * DD + 255) / 256, 256, 0, stream>>>(B, bat, g_sum, g_cnt);
    k_graph<<<NG * DD / 256, 256, 0, stream>>>(g_sum, g_cnt, Wg, g);
    k_readout<<<(NN + 255) / 256, 256, 0, stream>>>(B, g, bat, Wr, br, q);
}

// Round 3
// 801.540 us; speedup vs baseline: 2.3281x; 1.5141x over previous
//
#include <hip/hip_runtime.h>

#define NN 100000
#define NE 1200000
#define DIN 7
#define DD 64
#define NL 3
#define NG 64
#define PCH 16
#define NCHUNK (NN / PCH)   // 6250
#define NSB 391             // ceil(NN/256) scan blocks

// ---------------- node embed: out = relu(x @ Wn) ----------------
__global__ __launch_bounds__(256) void k_embed_node(const float* __restrict__ x,
        const float* __restrict__ Wn, float* __restrict__ out) {
    __shared__ float sW[DIN * DD];
    int t = threadIdx.x;
    for (int i = t; i < DIN * DD; i += 256) sW[i] = Wn[i];
    __syncthreads();
    int gid = blockIdx.x * 256 + t;          // exact grid: NN*DD/256
    int n = gid >> 6, d = gid & 63;
    const float* xr = x + n * DIN;
    float a = 0.f;
#pragma unroll
    for (int k = 0; k < DIN; ++k) a += xr[k] * sW[k * DD + d];
    out[gid] = fmaxf(a, 0.f);
}

// ---------------- y = x @ Wne[1:8,:]  (NO relu; w0*ea added per-edge) ----------------
__global__ __launch_bounds__(256) void k_embed_y(const float* __restrict__ x,
        const float* __restrict__ Wne, float* __restrict__ y) {
    __shared__ float sW[DIN * DD];
    int t = threadIdx.x;
    for (int i = t; i < DIN * DD; i += 256) {
        int k = i >> 6, d = i & 63;
        sW[i] = (d < 63) ? Wne[(k + 1) * 63 + d] : 0.f;
    }
    __syncthreads();
    int gid = blockIdx.x * 256 + t;          // exact grid
    int n = gid >> 6, d = gid & 63;
    const float* xr = x + n * DIN;
    float a = 0.f;
#pragma unroll
    for (int k = 0; k < DIN; ++k) a += xr[k] * sW[k * DD + d];
    y[gid] = a;                               // d==63 lane -> 0
}

// ---------------- CSR build ----------------
__global__ __launch_bounds__(256) void k_hist(const int* __restrict__ ei,
        int* __restrict__ cnti, int* __restrict__ degi) {
    int e = blockIdx.x * 256 + threadIdx.x;
    if (e >= NE) return;
    atomicAdd(&cnti[ei[e]], 1);
    atomicAdd(&degi[ei[NE + e]], 1);
}

__global__ __launch_bounds__(256) void k_scan1(const int* __restrict__ cnti,
        int* __restrict__ rowptr, int* __restrict__ bsum) {
    __shared__ int s[256];
    int t = threadIdx.x, i = blockIdx.x * 256 + t;
    int v = (i < NN) ? cnti[i] : 0;
    s[t] = v; __syncthreads();
    for (int off = 1; off < 256; off <<= 1) {
        int u = (t >= off) ? s[t - off] : 0; __syncthreads();
        s[t] += u; __syncthreads();
    }
    if (i < NN) rowptr[i] = s[t] - v;
    if (t == 255) bsum[blockIdx.x] = s[255];
}

__global__ __launch_bounds__(512) void k_scan2(const int* __restrict__ bsum,
        int* __restrict__ boff) {
    __shared__ int s[512];
    int t = threadIdx.x;
    int v = (t < NSB) ? bsum[t] : 0;
    s[t] = v; __syncthreads();
    for (int off = 1; off < 512; off <<= 1) {
        int u = (t >= off) ? s[t - off] : 0; __syncthreads();
        s[t] += u; __syncthreads();
    }
    boff[t] = s[t] - v;
}

__global__ __launch_bounds__(256) void k_scan3(int* __restrict__ rowptr,
        const int* __restrict__ boff) {
    int i = blockIdx.x * 256 + threadIdx.x;
    if (i < NN) rowptr[i] += boff[i >> 8];
    if (i == 0) rowptr[NN] = NE;
}

__global__ __launch_bounds__(256) void k_reorder(const int* __restrict__ ei,
        const float* __restrict__ ea, const int* __restrict__ rowptr,
        int* __restrict__ tmp, int* __restrict__ ecol, float* __restrict__ eat) {
    int e = blockIdx.x * 256 + threadIdx.x;
    if (e >= NE) return;
    int row = ei[e];
    int p = rowptr[row] + atomicAdd(&tmp[row], 1);
    ecol[p] = ei[NE + e];
    eat[p] = ea[e];
}

// ------- edge gather: nedm[n][d<63] = mean_e relu(ea*w0[d] + y[col][d]); [63]=deg -------
__global__ __launch_bounds__(256) void k_edge_gather(const int* __restrict__ rowptr,
        const int* __restrict__ ecol, const float* __restrict__ eat,
        const float* __restrict__ y, const int* __restrict__ degi,
        const float* __restrict__ Wne, float* __restrict__ nedm) {
    int t = threadIdx.x, wid = t >> 6, lane = t & 63;
    int n = blockIdx.x * 4 + wid;            // exact: NN/4
    float w0 = (lane < 63) ? Wne[lane] : 0.f;
    int s0 = rowptr[n], s1 = rowptr[n + 1];
    float acc = 0.f;
    for (int base = s0; base < s1; base += 64) {
        int m = min(64, s1 - base);
        int cc = (lane < m) ? ecol[base + lane] : 0;
        float aa = (lane < m) ? eat[base + lane] : 0.f;
        int j = 0;
        for (; j + 4 <= m; j += 4) {
            int c0 = __shfl(cc, j), c1 = __shfl(cc, j + 1);
            int c2 = __shfl(cc, j + 2), c3 = __shfl(cc, j + 3);
            float a0 = __shfl(aa, j), a1 = __shfl(aa, j + 1);
            float a2 = __shfl(aa, j + 2), a3 = __shfl(aa, j + 3);
            float v0 = y[(size_t)c0 * DD + lane], v1 = y[(size_t)c1 * DD + lane];
            float v2 = y[(size_t)c2 * DD + lane], v3 = y[(size_t)c3 * DD + lane];
            acc += fmaxf(fmaf(a0, w0, v0), 0.f);
            acc += fmaxf(fmaf(a1, w0, v1), 0.f);
            acc += fmaxf(fmaf(a2, w0, v2), 0.f);
            acc += fmaxf(fmaf(a3, w0, v3), 0.f);
        }
        for (; j < m; ++j) {
            int c = __shfl(cc, j);
            float a = __shfl(aa, j);
            acc += fmaxf(fmaf(a, w0, y[(size_t)c * DD + lane]), 0.f);
        }
    }
    float mean = acc / fmaxf((float)(s1 - s0), 1.f);
    nedm[(size_t)n * DD + lane] = (lane < 63) ? mean : (float)degi[n];
}

// ------- register-blocked GEMM: out = relu(in @ W), K=64; 32 nodes/block -------
// In-place safe (block reads only its own 32 rows, staged to LDS first).
__global__ __launch_bounds__(256) void k_gemm64(const float* __restrict__ in,
        const float* __restrict__ W, float* __restrict__ out) {
    __shared__ float sW[DD * DD];    // 16KB
    __shared__ float sI[32][DD];     // 8KB
    int t = threadIdx.x, wid = t >> 6, lane = t & 63;
    int nb = blockIdx.x * 32;        // exact: NN/32 = 3125
    for (int i = t; i < DD * DD / 4; i += 256)
        ((float4*)sW)[i] = ((const float4*)W)[i];
    for (int i = t; i < 32 * DD / 4; i += 256)
        ((float4*)sI)[i] = ((const float4*)(in + (size_t)nb * DD))[i];
    __syncthreads();
    float acc[8] = {0, 0, 0, 0, 0, 0, 0, 0};
    int n0 = wid * 8;
#pragma unroll 4
    for (int kc = 0; kc < 16; ++kc) {
        float w0 = sW[(4 * kc + 0) * DD + lane], w1 = sW[(4 * kc + 1) * DD + lane];
        float w2 = sW[(4 * kc + 2) * DD + lane], w3 = sW[(4 * kc + 3) * DD + lane];
#pragma unroll
        for (int j = 0; j < 8; ++j) {
            float4 v = *(const float4*)&sI[n0 + j][4 * kc];
            acc[j] = fmaf(v.x, w0, acc[j]); acc[j] = fmaf(v.y, w1, acc[j]);
            acc[j] = fmaf(v.z, w2, acc[j]); acc[j] = fmaf(v.w, w3, acc[j]);
        }
    }
#pragma unroll
    for (int j = 0; j < 8; ++j)
        out[(size_t)(nb + n0 + j) * DD + lane] = fmaxf(acc[j], 0.f);
}

// ------- message gather: xagg[n] = mean_e ea * xsrc[col]  (zero LDS, full occ) -------
__global__ __launch_bounds__(256) void k_gather(const int* __restrict__ rowptr,
        const int* __restrict__ ecol, const float* __restrict__ eat,
        const float* __restrict__ xsrc, float* __restrict__ xagg) {
    int t = threadIdx.x, wid = t >> 6, lane = t & 63;
    int n = blockIdx.x * 4 + wid;            // exact: NN/4
    int s0 = rowptr[n], s1 = rowptr[n + 1];
    float acc = 0.f;
    for (int base = s0; base < s1; base += 64) {
        int m = min(64, s1 - base);
        int cc = (lane < m) ? ecol[base + lane] : 0;
        float aa = (lane < m) ? eat[base + lane] : 0.f;
        int j = 0;
        for (; j + 4 <= m; j += 4) {
            int c0 = __shfl(cc, j), c1 = __shfl(cc, j + 1);
            int c2 = __shfl(cc, j + 2), c3 = __shfl(cc, j + 3);
            float a0 = __shfl(aa, j), a1 = __shfl(aa, j + 1);
            float a2 = __shfl(aa, j + 2), a3 = __shfl(aa, j + 3);
            float v0 = xsrc[(size_t)c0 * DD + lane], v1 = xsrc[(size_t)c1 * DD + lane];
            float v2 = xsrc[(size_t)c2 * DD + lane], v3 = xsrc[(size_t)c3 * DD + lane];
            acc = fmaf(a0, v0, acc); acc = fmaf(a1, v1, acc);
            acc = fmaf(a2, v2, acc); acc = fmaf(a3, v3, acc);
        }
        for (; j < m; ++j) {
            int c = __shfl(cc, j);
            float a = __shfl(aa, j);
            acc = fmaf(a, xsrc[(size_t)c * DD + lane], acc);
        }
    }
    xagg[(size_t)n * DD + lane] = acc / fmaxf((float)(s1 - s0), 1.f);
}

// ------- fused node update: m = relu([xagg,C]@Wm); xdst = relu([xsrc,m]@Wu) -------
// Reads/writes only its own 32 rows of xagg/xsrc/xdst -> xagg may alias xdst.
__global__ __launch_bounds__(256) void k_update(const float* __restrict__ xagg,
        const float* __restrict__ C, const float* __restrict__ xsrc,
        const float* __restrict__ Wm, const float* __restrict__ Wu,
        float* __restrict__ xdst) {
    __shared__ float sW[2 * DD * DD];    // 32KB
    __shared__ float sI[32][2 * DD];     // 16KB
    int t = threadIdx.x, wid = t >> 6, lane = t & 63;
    int nb = blockIdx.x * 32;            // exact: NN/32 = 3125
    for (int i = t; i < 2048; i += 256) ((float4*)sW)[i] = ((const float4*)Wm)[i];
    for (int i = t; i < 1024; i += 256) {
        int idx = i * 4, n = idx >> 7, k = idx & 127;
        const float* s = (k < DD) ? (xagg + (size_t)(nb + n) * DD + k)
                                  : (C + (size_t)(nb + n) * DD + (k - DD));
        *(float4*)&sI[n][k] = *(const float4*)s;
    }
    __syncthreads();
    float acc[8] = {0, 0, 0, 0, 0, 0, 0, 0};
    int n0 = wid * 8;
#pragma unroll 4
    for (int kc = 0; kc < 32; ++kc) {
        float w0 = sW[(4 * kc + 0) * DD + lane], w1 = sW[(4 * kc + 1) * DD + lane];
        float w2 = sW[(4 * kc + 2) * DD + lane], w3 = sW[(4 * kc + 3) * DD + lane];
#pragma unroll
        for (int j = 0; j < 8; ++j) {
            float4 v = *(const float4*)&sI[n0 + j][4 * kc];
            acc[j] = fmaf(v.x, w0, acc[j]); acc[j] = fmaf(v.y, w1, acc[j]);
            acc[j] = fmaf(v.z, w2, acc[j]); acc[j] = fmaf(v.w, w3, acc[j]);
        }
    }
    __syncthreads();                      // GEMM1 reads done
    for (int i = t; i < 2048; i += 256) ((float4*)sW)[i] = ((const float4*)Wu)[i];
    for (int i = t; i < 512; i += 256) {
        int idx = i * 4, n = idx >> 6, k = idx & 63;
        *(float4*)&sI[n][k] = *(const float4*)(xsrc + (size_t)(nb + n) * DD + k);
    }
#pragma unroll
    for (int j = 0; j < 8; ++j) sI[n0 + j][DD + lane] = fmaxf(acc[j], 0.f);
    __syncthreads();
    float acc2[8] = {0, 0, 0, 0, 0, 0, 0, 0};
#pragma unroll 4
    for (int kc = 0; kc < 32; ++kc) {
        float w0 = sW[(4 * kc + 0) * DD + lane], w1 = sW[(4 * kc + 1) * DD + lane];
        float w2 = sW[(4 * kc + 2) * DD + lane], w3 = sW[(4 * kc + 3) * DD + lane];
#pragma unroll
        for (int j = 0; j < 8; ++j) {
            float4 v = *(const float4*)&sI[n0 + j][4 * kc];
            acc2[j] = fmaf(v.x, w0, acc2[j]); acc2[j] = fmaf(v.y, w1, acc2[j]);
            acc2[j] = fmaf(v.z, w2, acc2[j]); acc2[j] = fmaf(v.w, w3, acc2[j]);
        }
    }
#pragma unroll
    for (int j = 0; j < 8; ++j)
        xdst[(size_t)(nb + n0 + j) * DD + lane] = fmaxf(acc2[j], 0.f);
}

// ---------- graph pool / graph GEMM / readout ----------
__global__ __launch_bounds__(256) void k_pool(const float* __restrict__ x_emb,
        const int* __restrict__ batch, float* __restrict__ g_sum,
        float* __restrict__ g_cnt) {
    int gid = blockIdx.x * 256 + threadIdx.x;
    int chunk = gid >> 6, d = gid & 63;
    if (chunk >= NCHUNK) return;
    int n0 = chunk * PCH;
    int curb = batch[n0];
    float s = 0.f, c = 0.f;
    for (int n = n0; n < n0 + PCH; ++n) {
        int b = batch[n];
        if (b != curb) {
            atomicAdd(&g_sum[curb * DD + d], s);
            if (d == 0) atomicAdd(&g_cnt[curb], c);
            s = 0.f; c = 0.f; curb = b;
        }
        s += x_emb[(size_t)n * DD + d];
        c += 1.f;
    }
    atomicAdd(&g_sum[curb * DD + d], s);
    if (d == 0) atomicAdd(&g_cnt[curb], c);
}

__global__ __launch_bounds__(256) void k_graph(const float* __restrict__ g_sum,
        const float* __restrict__ g_cnt, const float* __restrict__ Wg,
        float* __restrict__ g) {
    int gid = blockIdx.x * 256 + threadIdx.x;  // exact: 16 blocks
    int gi = gid >> 6, d = gid & 63;
    float c = fmaxf(g_cnt[gi], 1.f);
    float o = 0.f;
#pragma unroll 8
    for (int k = 0; k < DD; ++k) o += (g_sum[gi * DD + k] / c) * Wg[k * DD + d];
    g[gid] = fmaxf(o, 0.f);
}

__global__ __launch_bounds__(256) void k_readout(const float* __restrict__ x_emb,
        const float* __restrict__ g, const int* __restrict__ batch,
        const float* __restrict__ Wr, const float* __restrict__ br,
        float* __restrict__ q) {
    __shared__ float sWr[2 * DD];
    int t = threadIdx.x;
    if (t < 2 * DD) sWr[t] = Wr[t];
    __syncthreads();
    int n = blockIdx.x * 256 + t;
    if (n >= NN) return;
    int b = batch[n];
    const float* gr = g + b * DD;
    const float* xr = x_emb + (size_t)n * DD;
    float o = br[0];
#pragma unroll 8
    for (int k = 0; k < DD; ++k) o += gr[k] * sWr[k];
#pragma unroll 8
    for (int k = 0; k < DD; ++k) o += xr[k] * sWr[DD + k];
    q[n] = o;
}

extern "C" void kernel_launch(void* const* d_in, const int* in_sizes, int n_in,
                              void* d_out, int out_size, void* d_ws, size_t ws_size,
                              hipStream_t stream) {
    const float* x   = (const float*)d_in[0];
    const int*   ei  = (const int*)d_in[1];
    const float* ea  = (const float*)d_in[2];
    const int*   bat = (const int*)d_in[3];
    const float* Wn  = (const float*)d_in[4];
    const float* Wne = (const float*)d_in[5];
    const float* Wa  = (const float*)d_in[6];
    const float* Wm  = (const float*)d_in[7];
    const float* Wu  = (const float*)d_in[8];
    const float* Wg  = (const float*)d_in[9];
    const float* Wr  = (const float*)d_in[10];
    const float* br  = (const float*)d_in[11];
    float* q = (float*)d_out;

    // ---- workspace layout (same footprint as round 1) ----
    float* A     = (float*)d_ws;                  // NN*DD  x_emb ping
    float* B     = A + (size_t)NN * DD;           // NN*DD  x_emb pong; also y; also xagg(l0,l2)
    float* C     = B + (size_t)NN * DD;           // NN*DD  x_agg_emb; also nedm (in-place gemm64)
    float* eat   = C + (size_t)NN * DD;           // NE
    float* g_sum = eat + NE;                      // NG*DD
    float* g_cnt = g_sum + NG * DD;               // NG
    float* g     = g_cnt + NG;                    // NG*DD
    int* cnti    = (int*)(g + NG * DD);           // NN
    int* degi    = cnti + NN;                     // NN
    int* tmp     = degi + NN;                     // NN
    int* rowptr  = tmp + NN;                      // NN+1
    int* bsum    = rowptr + NN + 1;               // 512
    int* boff    = bsum + 512;                    // 512
    int* ecol    = boff + 512;                    // NE

    hipMemsetAsync(cnti, 0, (size_t)3 * NN * sizeof(int), stream);
    hipMemsetAsync(g_sum, 0, (size_t)(NG * DD + NG) * sizeof(float), stream);

    const int EB = (NE + 255) / 256;
    k_hist<<<EB, 256, 0, stream>>>(ei, cnti, degi);
    k_scan1<<<NSB, 256, 0, stream>>>(cnti, rowptr, bsum);
    k_scan2<<<1, 512, 0, stream>>>(bsum, boff);
    k_scan3<<<NSB, 256, 0, stream>>>(rowptr, boff);
    k_reorder<<<EB, 256, 0, stream>>>(ei, ea, rowptr, tmp, ecol, eat);

    // edge-embedding path: y (in B) -> nedm (in C) -> C = relu(nedm @ Wa) in place
    k_embed_y<<<NN * DD / 256, 256, 0, stream>>>(x, Wne, B);
    k_edge_gather<<<NN / 4, 256, 0, stream>>>(rowptr, ecol, eat, B, degi, Wne, C);
    k_gemm64<<<NN / 32, 256, 0, stream>>>(C, Wa, C);

    // node embedding into A (B is free after k_edge_gather)
    k_embed_node<<<NN * DD / 256, 256, 0, stream>>>(x, Wn, A);

    for (int l = 0; l < NL; ++l) {
        const float* src = (l & 1) ? B : A;
        float* dst = (l & 1) ? A : B;
        // gather reads src cross-block, writes dst rows; update reads/writes own rows only
        k_gather<<<NN / 4, 256, 0, stream>>>(rowptr, ecol, eat, src, dst);
        k_update<<<NN / 32, 256, 0, stream>>>(dst, C, src,
            Wm + (size_t)l * 2 * DD * DD, Wu + (size_t)l * 2 * DD * DD, dst);
    }
    // result in B after l=2

    k_pool<<<(NCHUNK * DD + 255) / 256, 256, 0, stream>>>(B, bat, g_sum, g_cnt);
    k_graph<<<NG * DD / 256, 256, 0, stream>>>(g_sum, g_cnt, Wg, g);
    k_readout<<<(NN + 255) / 256, 256, 0, stream>>>(B, g, bat, Wr, br, q);
}

// Round 4
// 659.072 us; speedup vs baseline: 2.8314x; 1.2162x over previous
//
#include <hip/hip_runtime.h>

#define NN 100000
#define NNP 100032          // padded to 64-node tiles
#define NE 1200000
#define DIN 7
#define DD 64
#define NL 3
#define NG 64
#define PCH 16
#define NCHUNK (NN / PCH)   // 6250
#define NSB 391             // ceil(NN/256) scan blocks

typedef float f32x4 __attribute__((ext_vector_type(4)));

__device__ inline f32x4 relu4(f32x4 v) {
    v[0] = fmaxf(v[0], 0.f); v[1] = fmaxf(v[1], 0.f);
    v[2] = fmaxf(v[2], 0.f); v[3] = fmaxf(v[3], 0.f);
    return v;
}

// ------------- fused embed: A = relu(x@Wn), Yb = x@Wne[1:8,:] (col63=0, no relu) -------------
__global__ __launch_bounds__(256) void k_embed_xy(const float* __restrict__ x,
        const float* __restrict__ Wn, const float* __restrict__ Wne,
        float* __restrict__ A, float* __restrict__ Yb) {
    __shared__ float sWn[DIN * DD];
    __shared__ float sWy[DIN * DD];
    int t = threadIdx.x;
    for (int i = t; i < DIN * DD; i += 256) {
        sWn[i] = Wn[i];
        int k = i >> 6, d = i & 63;
        sWy[i] = (d < 63) ? Wne[(k + 1) * 63 + d] : 0.f;
    }
    __syncthreads();
    int gid = blockIdx.x * 256 + t;          // exact grid: NN*DD/256
    int n = gid >> 6, d = gid & 63;
    const float* xr = x + n * DIN;
    float a = 0.f, y = 0.f;
#pragma unroll
    for (int k = 0; k < DIN; ++k) {
        float xv = xr[k];
        a = fmaf(xv, sWn[k * DD + d], a);
        y = fmaf(xv, sWy[k * DD + d], y);
    }
    A[gid] = fmaxf(a, 0.f);
    Yb[gid] = y;
}

// ---------------- CSR build ----------------
__global__ __launch_bounds__(256) void k_hist(const int* __restrict__ ei,
        int* __restrict__ cnti, int* __restrict__ degi) {
    int e = blockIdx.x * 256 + threadIdx.x;
    if (e >= NE) return;
    atomicAdd(&cnti[ei[e]], 1);
    atomicAdd(&degi[ei[NE + e]], 1);
}

__global__ __launch_bounds__(256) void k_scan1(const int* __restrict__ cnti,
        int* __restrict__ rowptr, int* __restrict__ bsum) {
    __shared__ int s[256];
    int t = threadIdx.x, i = blockIdx.x * 256 + t;
    int v = (i < NN) ? cnti[i] : 0;
    s[t] = v; __syncthreads();
    for (int off = 1; off < 256; off <<= 1) {
        int u = (t >= off) ? s[t - off] : 0; __syncthreads();
        s[t] += u; __syncthreads();
    }
    if (i < NN) rowptr[i] = s[t] - v;
    if (t == 255) bsum[blockIdx.x] = s[255];
}

__global__ __launch_bounds__(512) void k_scan2(const int* __restrict__ bsum,
        int* __restrict__ boff) {
    __shared__ int s[512];
    int t = threadIdx.x;
    int v = (t < NSB) ? bsum[t] : 0;
    s[t] = v; __syncthreads();
    for (int off = 1; off < 512; off <<= 1) {
        int u = (t >= off) ? s[t - off] : 0; __syncthreads();
        s[t] += u; __syncthreads();
    }
    boff[t] = s[t] - v;
}

__global__ __launch_bounds__(256) void k_scan3(int* __restrict__ rowptr,
        const int* __restrict__ boff) {
    int i = blockIdx.x * 256 + threadIdx.x;
    if (i < NN) rowptr[i] += boff[i >> 8];
    if (i == 0) rowptr[NN] = NE;
}

__global__ __launch_bounds__(256) void k_reorder(const int* __restrict__ ei,
        const float* __restrict__ ea, const int* __restrict__ rowptr,
        int* __restrict__ tmp, int* __restrict__ ecol, float* __restrict__ eat) {
    int e = blockIdx.x * 256 + threadIdx.x;
    if (e >= NE) return;
    int row = ei[e];
    int p = rowptr[row] + atomicAdd(&tmp[row], 1);
    ecol[p] = ei[NE + e];
    eat[p] = ea[e];
}

// ------- fused edge gather + layer-0 message gather (one CSR pass) -------
// nedm[n][d<63] = mean_e relu(ea*w0[d] + y[col][d]); [63]=deg
// xagg0[n][d]   = mean_e ea * A[col][d]
__global__ __launch_bounds__(256) void k_fused_edge(const int* __restrict__ rowptr,
        const int* __restrict__ ecol, const float* __restrict__ eat,
        const float* __restrict__ y, const float* __restrict__ A,
        const int* __restrict__ degi, const float* __restrict__ Wne,
        float* __restrict__ nedm, float* __restrict__ xagg0) {
    int t = threadIdx.x, wid = t >> 6, lane = t & 63;
    int n = blockIdx.x * 4 + wid;            // exact: NN/4
    float w0 = (lane < 63) ? Wne[lane] : 0.f;
    int s0 = rowptr[n], s1 = rowptr[n + 1];
    float accn = 0.f, accx = 0.f;
    for (int base = s0; base < s1; base += 64) {
        int m = min(64, s1 - base);
        int cc = (lane < m) ? ecol[base + lane] : 0;
        float aa = (lane < m) ? eat[base + lane] : 0.f;
        int j = 0;
        for (; j + 4 <= m; j += 4) {         // 8 loads in flight
            int c0 = __shfl(cc, j), c1 = __shfl(cc, j + 1);
            int c2 = __shfl(cc, j + 2), c3 = __shfl(cc, j + 3);
            float a0 = __shfl(aa, j), a1 = __shfl(aa, j + 1);
            float a2 = __shfl(aa, j + 2), a3 = __shfl(aa, j + 3);
            float y0 = y[(size_t)c0 * DD + lane], y1 = y[(size_t)c1 * DD + lane];
            float y2 = y[(size_t)c2 * DD + lane], y3 = y[(size_t)c3 * DD + lane];
            float v0 = A[(size_t)c0 * DD + lane], v1 = A[(size_t)c1 * DD + lane];
            float v2 = A[(size_t)c2 * DD + lane], v3 = A[(size_t)c3 * DD + lane];
            accn += fmaxf(fmaf(a0, w0, y0), 0.f);
            accn += fmaxf(fmaf(a1, w0, y1), 0.f);
            accn += fmaxf(fmaf(a2, w0, y2), 0.f);
            accn += fmaxf(fmaf(a3, w0, y3), 0.f);
            accx = fmaf(a0, v0, accx); accx = fmaf(a1, v1, accx);
            accx = fmaf(a2, v2, accx); accx = fmaf(a3, v3, accx);
        }
        for (; j < m; ++j) {
            int c = __shfl(cc, j);
            float a = __shfl(aa, j);
            accn += fmaxf(fmaf(a, w0, y[(size_t)c * DD + lane]), 0.f);
            accx = fmaf(a, A[(size_t)c * DD + lane], accx);
        }
    }
    float inv = 1.f / fmaxf((float)(s1 - s0), 1.f);
    nedm[(size_t)n * DD + lane] = (lane < 63) ? accn * inv : (float)degi[n];
    xagg0[(size_t)n * DD + lane] = accx * inv;
}

// ------- fallback (no Y buffer): edge gather only -------
__global__ __launch_bounds__(256) void k_edge_gather(const int* __restrict__ rowptr,
        const int* __restrict__ ecol, const float* __restrict__ eat,
        const float* __restrict__ y, const int* __restrict__ degi,
        const float* __restrict__ Wne, float* __restrict__ nedm) {
    int t = threadIdx.x, wid = t >> 6, lane = t & 63;
    int n = blockIdx.x * 4 + wid;
    float w0 = (lane < 63) ? Wne[lane] : 0.f;
    int s0 = rowptr[n], s1 = rowptr[n + 1];
    float acc = 0.f;
    for (int base = s0; base < s1; base += 64) {
        int m = min(64, s1 - base);
        int cc = (lane < m) ? ecol[base + lane] : 0;
        float aa = (lane < m) ? eat[base + lane] : 0.f;
        for (int j = 0; j < m; ++j) {
            int c = __shfl(cc, j);
            float a = __shfl(aa, j);
            acc += fmaxf(fmaf(a, w0, y[(size_t)c * DD + lane]), 0.f);
        }
    }
    float mean = acc / fmaxf((float)(s1 - s0), 1.f);
    nedm[(size_t)n * DD + lane] = (lane < 63) ? mean : (float)degi[n];
}

// ------- register-blocked GEMM: out = relu(in @ W), K=64; 32 nodes/block -------
__global__ __launch_bounds__(256) void k_gemm64(const float* __restrict__ in,
        const float* __restrict__ W, float* __restrict__ out) {
    __shared__ float sW[DD * DD];
    __shared__ float sI[32][DD];
    int t = threadIdx.x, wid = t >> 6, lane = t & 63;
    int nb = blockIdx.x * 32;        // exact: NN/32 = 3125
    for (int i = t; i < DD * DD / 4; i += 256)
        ((float4*)sW)[i] = ((const float4*)W)[i];
    for (int i = t; i < 32 * DD / 4; i += 256)
        ((float4*)sI)[i] = ((const float4*)(in + (size_t)nb * DD))[i];
    __syncthreads();
    float acc[8] = {0, 0, 0, 0, 0, 0, 0, 0};
    int n0 = wid * 8;
#pragma unroll 4
    for (int kc = 0; kc < 16; ++kc) {
        float w0 = sW[(4 * kc + 0) * DD + lane], w1 = sW[(4 * kc + 1) * DD + lane];
        float w2 = sW[(4 * kc + 2) * DD + lane], w3 = sW[(4 * kc + 3) * DD + lane];
#pragma unroll
        for (int j = 0; j < 8; ++j) {
            float4 v = *(const float4*)&sI[n0 + j][4 * kc];
            acc[j] = fmaf(v.x, w0, acc[j]); acc[j] = fmaf(v.y, w1, acc[j]);
            acc[j] = fmaf(v.z, w2, acc[j]); acc[j] = fmaf(v.w, w3, acc[j]);
        }
    }
#pragma unroll
    for (int j = 0; j < 8; ++j)
        out[(size_t)(nb + n0 + j) * DD + lane] = fmaxf(acc[j], 0.f);
}

// ------- message gather: xagg[n] = mean_e ea * xsrc[col], 8-deep pipeline -------
__global__ __launch_bounds__(256) void k_gather(const int* __restrict__ rowptr,
        const int* __restrict__ ecol, const float* __restrict__ eat,
        const float* __restrict__ xsrc, float* __restrict__ xagg) {
    int t = threadIdx.x, wid = t >> 6, lane = t & 63;
    int n = blockIdx.x * 4 + wid;            // exact: NN/4
    int s0 = rowptr[n], s1 = rowptr[n + 1];
    float acc = 0.f;
    for (int base = s0; base < s1; base += 64) {
        int m = min(64, s1 - base);
        int cc = (lane < m) ? ecol[base + lane] : 0;
        float aa = (lane < m) ? eat[base + lane] : 0.f;
        int j = 0;
        for (; j + 8 <= m; j += 8) {
            int c[8]; float a[8], v[8];
#pragma unroll
            for (int u = 0; u < 8; ++u) { c[u] = __shfl(cc, j + u); a[u] = __shfl(aa, j + u); }
#pragma unroll
            for (int u = 0; u < 8; ++u) v[u] = xsrc[(size_t)c[u] * DD + lane];
#pragma unroll
            for (int u = 0; u < 8; ++u) acc = fmaf(a[u], v[u], acc);
        }
        for (; j < m; ++j) {
            int c = __shfl(cc, j);
            float a = __shfl(aa, j);
            acc = fmaf(a, xsrc[(size_t)c * DD + lane], acc);
        }
    }
    xagg[(size_t)n * DD + lane] = acc / fmaxf((float)(s1 - s0), 1.f);
}

// ------- node update, 4x4 register tile, 64 nodes/block, K split in halves -------
// m = relu([xagg,C]@Wm); xdst = relu([xsrc,m]@Wu).  In-place safe on xagg==xdst.
__global__ __launch_bounds__(256) void k_update(const float* __restrict__ xagg,
        const float* __restrict__ C, const float* __restrict__ xsrc,
        const float* __restrict__ Wm, const float* __restrict__ Wu,
        float* __restrict__ xdst) {
    __shared__ __align__(16) float sX[64 * 68];   // 64 rows, 68-float stride (pad 4)
    __shared__ __align__(16) float sW[64 * 64];   // one K-half of weights
    f32x4* sX4 = (f32x4*)sX;
    f32x4* sW4 = (f32x4*)sW;
    int t = threadIdx.x, tx = t & 15, ty = t >> 4;
    int nb = blockIdx.x * 64;                     // grid NNP/64 = 1563

    auto stageX = [&](const float* __restrict__ src) {
        const f32x4* g = (const f32x4*)src;
        for (int i = t; i < 1024; i += 256) {
            int r = i >> 4, c = i & 15;
            sX4[r * 17 + c] = g[(size_t)(nb + r) * 16 + c];
        }
    };
    auto stageW = [&](const float* __restrict__ w) {
        const f32x4* g = (const f32x4*)w;
        for (int i = t; i < 1024; i += 256) sW4[i] = g[i];
    };
    auto compute = [&](f32x4* acc) {
        const f32x4* x0 = sX4 + (4 * ty + 0) * 17;
        const f32x4* x1 = sX4 + (4 * ty + 1) * 17;
        const f32x4* x2 = sX4 + (4 * ty + 2) * 17;
        const f32x4* x3 = sX4 + (4 * ty + 3) * 17;
#pragma unroll 4
        for (int kc = 0; kc < 16; ++kc) {
            f32x4 a0 = x0[kc], a1 = x1[kc], a2 = x2[kc], a3 = x3[kc];
            f32x4 w0 = sW4[(4 * kc + 0) * 16 + tx];
            f32x4 w1 = sW4[(4 * kc + 1) * 16 + tx];
            f32x4 w2 = sW4[(4 * kc + 2) * 16 + tx];
            f32x4 w3 = sW4[(4 * kc + 3) * 16 + tx];
            acc[0] += a0[0] * w0; acc[0] += a0[1] * w1; acc[0] += a0[2] * w2; acc[0] += a0[3] * w3;
            acc[1] += a1[0] * w0; acc[1] += a1[1] * w1; acc[1] += a1[2] * w2; acc[1] += a1[3] * w3;
            acc[2] += a2[0] * w0; acc[2] += a2[1] * w1; acc[2] += a2[2] * w2; acc[2] += a2[3] * w3;
            acc[3] += a3[0] * w0; acc[3] += a3[1] * w1; acc[3] += a3[2] * w2; acc[3] += a3[3] * w3;
        }
    };

    f32x4 acc1[4] = {}, acc2[4] = {};
    // GEMM1 half 0: xagg @ Wm[0:64]
    stageX(xagg); stageW(Wm);
    __syncthreads(); compute(acc1); __syncthreads();
    // GEMM1 half 1: C @ Wm[64:128]
    stageX(C); stageW(Wm + 4096);
    __syncthreads(); compute(acc1); __syncthreads();
    f32x4 mm[4];
#pragma unroll
    for (int j = 0; j < 4; ++j) mm[j] = relu4(acc1[j]);
    // GEMM2 half 0: xsrc @ Wu[0:64]
    stageX(xsrc); stageW(Wu);
    __syncthreads(); compute(acc2); __syncthreads();
    // GEMM2 half 1: m @ Wu[64:128]  (m written from registers into sX)
#pragma unroll
    for (int j = 0; j < 4; ++j) sX4[(4 * ty + j) * 17 + tx] = mm[j];
    stageW(Wu + 4096);
    __syncthreads(); compute(acc2);
    f32x4* gout = (f32x4*)xdst;
#pragma unroll
    for (int j = 0; j < 4; ++j)
        gout[(size_t)(nb + 4 * ty + j) * 16 + tx] = relu4(acc2[j]);
}

// ---------- graph pool / graph GEMM / readout ----------
__global__ __launch_bounds__(256) void k_pool(const float* __restrict__ x_emb,
        const int* __restrict__ batch, float* __restrict__ g_sum,
        float* __restrict__ g_cnt) {
    int gid = blockIdx.x * 256 + threadIdx.x;
    int chunk = gid >> 6, d = gid & 63;
    if (chunk >= NCHUNK) return;
    int n0 = chunk * PCH;
    int curb = batch[n0];
    float s = 0.f, c = 0.f;
    for (int n = n0; n < n0 + PCH; ++n) {
        int b = batch[n];
        if (b != curb) {
            atomicAdd(&g_sum[curb * DD + d], s);
            if (d == 0) atomicAdd(&g_cnt[curb], c);
            s = 0.f; c = 0.f; curb = b;
        }
        s += x_emb[(size_t)n * DD + d];
        c += 1.f;
    }
    atomicAdd(&g_sum[curb * DD + d], s);
    if (d == 0) atomicAdd(&g_cnt[curb], c);
}

__global__ __launch_bounds__(256) void k_graph(const float* __restrict__ g_sum,
        const float* __restrict__ g_cnt, const float* __restrict__ Wg,
        float* __restrict__ g) {
    int gid = blockIdx.x * 256 + threadIdx.x;  // exact: 16 blocks
    int gi = gid >> 6, d = gid & 63;
    float c = fmaxf(g_cnt[gi], 1.f);
    float o = 0.f;
#pragma unroll 8
    for (int k = 0; k < DD; ++k) o += (g_sum[gi * DD + k] / c) * Wg[k * DD + d];
    g[gid] = fmaxf(o, 0.f);
}

__global__ __launch_bounds__(256) void k_readout(const float* __restrict__ x_emb,
        const float* __restrict__ g, const int* __restrict__ batch,
        const float* __restrict__ Wr, const float* __restrict__ br,
        float* __restrict__ q) {
    __shared__ float sWr[2 * DD];
    int t = threadIdx.x;
    if (t < 2 * DD) sWr[t] = Wr[t];
    __syncthreads();
    int n = blockIdx.x * 256 + t;
    if (n >= NN) return;
    int b = batch[n];
    const float* gr = g + b * DD;
    const float* xr = x_emb + (size_t)n * DD;
    float o = br[0];
#pragma unroll 8
    for (int k = 0; k < DD; ++k) o += gr[k] * sWr[k];
#pragma unroll 8
    for (int k = 0; k < DD; ++k) o += xr[k] * sWr[DD + k];
    q[n] = o;
}

extern "C" void kernel_launch(void* const* d_in, const int* in_sizes, int n_in,
                              void* d_out, int out_size, void* d_ws, size_t ws_size,
                              hipStream_t stream) {
    const float* x   = (const float*)d_in[0];
    const int*   ei  = (const int*)d_in[1];
    const float* ea  = (const float*)d_in[2];
    const int*   bat = (const int*)d_in[3];
    const float* Wn  = (const float*)d_in[4];
    const float* Wne = (const float*)d_in[5];
    const float* Wa  = (const float*)d_in[6];
    const float* Wm  = (const float*)d_in[7];
    const float* Wu  = (const float*)d_in[8];
    const float* Wg  = (const float*)d_in[9];
    const float* Wr  = (const float*)d_in[10];
    const float* br  = (const float*)d_in[11];
    float* q = (float*)d_out;

    const size_t FB = (size_t)NNP * DD;          // big buffer elems
    // does a 4th big buffer (Y) fit?
    size_t need4 = (4 * FB + NE + 2 * (size_t)NG * DD + NG) * 4
                 + ((size_t)3 * NN + NN + 1 + 1024 + NE) * 4;
    bool fused = ws_size >= need4;

    float* A = (float*)d_ws;                     // x_emb ping
    float* B = A + FB;                           // x_emb pong
    float* C = B + FB;                           // nedm -> x_agg_emb
    float* cur = C + FB;
    float* Y = fused ? cur : B;                  // y buffer (or alias B in fallback)
    if (fused) cur += FB;
    float* eat   = cur;                          // NE
    float* g_sum = eat + NE;                     // NG*DD
    float* g_cnt = g_sum + NG * DD;              // NG
    float* g     = g_cnt + NG;                   // NG*DD
    int* cnti    = (int*)(g + NG * DD);          // NN
    int* degi    = cnti + NN;                    // NN
    int* tmp     = degi + NN;                    // NN
    int* rowptr  = tmp + NN;                     // NN+1
    int* bsum    = rowptr + NN + 1;              // 512
    int* boff    = bsum + 512;                   // 512
    int* ecol    = boff + 512;                   // NE

    hipMemsetAsync(cnti, 0, (size_t)3 * NN * sizeof(int), stream);
    hipMemsetAsync(g_sum, 0, (size_t)(NG * DD + NG) * sizeof(float), stream);

    const int EB = (NE + 255) / 256;
    k_hist<<<EB, 256, 0, stream>>>(ei, cnti, degi);
    k_scan1<<<NSB, 256, 0, stream>>>(cnti, rowptr, bsum);
    k_scan2<<<1, 512, 0, stream>>>(bsum, boff);
    k_scan3<<<NSB, 256, 0, stream>>>(rowptr, boff);
    k_reorder<<<EB, 256, 0, stream>>>(ei, ea, rowptr, tmp, ecol, eat);

    k_embed_xy<<<NN * DD / 256, 256, 0, stream>>>(x, Wn, Wne, A, Y);

    if (fused) {
        // one CSR pass: nedm -> C, layer-0 xagg -> B
        k_fused_edge<<<NN / 4, 256, 0, stream>>>(rowptr, ecol, eat, Y, A, degi, Wne, C, B);
        k_gemm64<<<NN / 32, 256, 0, stream>>>(C, Wa, C);
    } else {
        k_edge_gather<<<NN / 4, 256, 0, stream>>>(rowptr, ecol, eat, Y, degi, Wne, C);
        k_gemm64<<<NN / 32, 256, 0, stream>>>(C, Wa, C);
        k_gather<<<NN / 4, 256, 0, stream>>>(rowptr, ecol, eat, A, B);  // L0 xagg -> B
    }

    const int UB = NNP / 64;                     // 1563
    // L0: xagg=B, xsrc=A -> B
    k_update<<<UB, 256, 0, stream>>>(B, C, A, Wm, Wu, B);
    // L1: gather B->A; xagg=A, xsrc=B -> A
    k_gather<<<NN / 4, 256, 0, stream>>>(rowptr, ecol, eat, B, A);
    k_update<<<UB, 256, 0, stream>>>(A, C, B, Wm + 8192, Wu + 8192, A);
    // L2: gather A->B; xagg=B, xsrc=A -> B
    k_gather<<<NN / 4, 256, 0, stream>>>(rowptr, ecol, eat, A, B);
    k_update<<<UB, 256, 0, stream>>>(B, C, A, Wm + 16384, Wu + 16384, B);

    k_pool<<<(NCHUNK * DD + 255) / 256, 256, 0, stream>>>(B, bat, g_sum, g_cnt);
    k_graph<<<NG * DD / 256, 256, 0, stream>>>(g_sum, g_cnt, Wg, g);
    k_readout<<<(NN + 255) / 256, 256, 0, stream>>>(B, g, bat, Wr, br, q);
}

// Round 5
// 557.763 us; speedup vs baseline: 3.3456x; 1.1816x over previous
//
#include <hip/hip_runtime.h>

#define NN 100000
#define NNP 100032          // padded to 64-node tiles
#define NE 1200000
#define DIN 7
#define DD 64
#define NL 3
#define NG 64
#define PCH 16
#define NCHUNK (NN / PCH)   // 6250
#define RB 782              // row/col buckets: 99999>>7 = 781
#define BCAP 2048           // per-bucket capacity (mean 1535, std ~39)
#define B1 128              // pass-1 blocks
#define CHUNK (NE / B1)     // 9375 exact

typedef float f32x4 __attribute__((ext_vector_type(4)));

__device__ inline f32x4 relu4(f32x4 v) {
    v[0] = fmaxf(v[0], 0.f); v[1] = fmaxf(v[1], 0.f);
    v[2] = fmaxf(v[2], 0.f); v[3] = fmaxf(v[3], 0.f);
    return v;
}

// ------------- fused embed: A = relu(x@Wn), Yb = x@Wne[1:8,:] (col63=0, no relu) -------------
__global__ __launch_bounds__(256) void k_embed_xy(const float* __restrict__ x,
        const float* __restrict__ Wn, const float* __restrict__ Wne,
        float* __restrict__ A, float* __restrict__ Yb) {
    __shared__ float sWn[DIN * DD];
    __shared__ float sWy[DIN * DD];
    int t = threadIdx.x;
    for (int i = t; i < DIN * DD; i += 256) {
        sWn[i] = Wn[i];
        int k = i >> 6, d = i & 63;
        sWy[i] = (d < 63) ? Wne[(k + 1) * 63 + d] : 0.f;
    }
    __syncthreads();
    int gid = blockIdx.x * 256 + t;          // exact grid: NN*DD/256
    int n = gid >> 6, d = gid & 63;
    const float* xr = x + n * DIN;
    float a = 0.f, y = 0.f;
#pragma unroll
    for (int k = 0; k < DIN; ++k) {
        float xv = xr[k];
        a = fmaf(xv, sWn[k * DD + d], a);
        y = fmaf(xv, sWy[k * DD + d], y);
    }
    A[gid] = fmaxf(a, 0.f);
    Yb[gid] = y;
}

// ---------------- CSR build via LDS bucket sort (no scattered global atomics) ----------------
// Pass 1: count buckets in LDS, reserve ranges, scatter records into padded bucket regions.
__global__ __launch_bounds__(256) void k_bucket(const int* __restrict__ ei,
        const float* __restrict__ ea, int* __restrict__ gR, int* __restrict__ gC,
        uint4* __restrict__ tmpR, int* __restrict__ tmpC) {
    __shared__ int hR[RB], hC[RB];
    int t = threadIdx.x;
    for (int i = t; i < RB; i += 256) { hR[i] = 0; hC[i] = 0; }
    __syncthreads();
    int e0 = blockIdx.x * CHUNK, e1 = e0 + CHUNK;
    for (int e = e0 + t; e < e1; e += 256) {
        atomicAdd(&hR[ei[e] >> 7], 1);
        atomicAdd(&hC[ei[NE + e] >> 7], 1);
    }
    __syncthreads();
    for (int b = t; b < RB; b += 256) {
        int n = hR[b]; hR[b] = n ? atomicAdd(&gR[b], n) : 0;
        n = hC[b];     hC[b] = n ? atomicAdd(&gC[b], n) : 0;
    }
    __syncthreads();
    for (int e = e0 + t; e < e1; e += 256) {
        int r = ei[e], c = ei[NE + e];
        float a = ea[e];
        int br = r >> 7, bc = c >> 7;
        int ir = atomicAdd(&hR[br], 1);   // LDS: absolute in-bucket index
        if (ir < BCAP) tmpR[(size_t)br * BCAP + ir] = make_uint4((unsigned)r, (unsigned)c, __float_as_uint(a), 0u);
        int ic = atomicAdd(&hC[bc], 1);
        if (ic < BCAP) tmpC[(size_t)bc * BCAP + ic] = c;
    }
}

// exclusive scan of 782 row-bucket totals
__global__ __launch_bounds__(1024) void k_bscan(const int* __restrict__ gR,
        int* __restrict__ bsR) {
    __shared__ int s[1024];
    int t = threadIdx.x;
    int v = (t < RB) ? gR[t] : 0;
    s[t] = v; __syncthreads();
    for (int off = 1; off < 1024; off <<= 1) {
        int u = (t >= off) ? s[t - off] : 0; __syncthreads();
        s[t] += u; __syncthreads();
    }
    if (t < RB) bsR[t] = s[t] - v;
}

// Pass 2: per-bucket counting sort fully in LDS; writes rowptr, ecol, eat.
__global__ __launch_bounds__(256) void k_sortbucket(const int* __restrict__ gR,
        const int* __restrict__ bsR, const uint4* __restrict__ tmpR,
        int* __restrict__ rowptr, int* __restrict__ ecol, float* __restrict__ eat) {
    __shared__ uint4 sbuf[BCAP];              // 32 KB
    __shared__ int cnt128[128], off128[128], sscan[128];
    int b = blockIdx.x, t = threadIdx.x;
    int cnt = min(gR[b], BCAP);
    int base = bsR[b];
    if (t < 128) cnt128[t] = 0;
    __syncthreads();
    for (int i = t; i < cnt; i += 256) {
        uint4 rec = tmpR[(size_t)b * BCAP + i];
        sbuf[i] = rec;
        atomicAdd(&cnt128[rec.x & 127], 1);
    }
    __syncthreads();
    if (t < 128) sscan[t] = cnt128[t];
    __syncthreads();
    for (int off = 1; off < 128; off <<= 1) {
        int u = (t < 128 && t >= off) ? sscan[t - off] : 0;
        __syncthreads();
        if (t < 128) sscan[t] += u;
        __syncthreads();
    }
    if (t < 128) {
        int excl = sscan[t] - cnt128[t];
        off128[t] = excl;
        int row = (b << 7) + t;
        if (row <= NN) rowptr[row] = base + excl;   // bucket 781 local 32 -> rowptr[NN]=NE
    }
    __syncthreads();
    for (int i = t; i < cnt; i += 256) {
        uint4 rec = sbuf[i];
        int p = atomicAdd(&off128[rec.x & 127], 1);
        ecol[base + p] = (int)rec.y;
        eat[base + p] = __uint_as_float(rec.z);
    }
}

// per-bucket in-degree counts, dense write
__global__ __launch_bounds__(256) void k_degbucket(const int* __restrict__ gC,
        const int* __restrict__ tmpC, int* __restrict__ degi) {
    __shared__ int cnt128[128];
    int b = blockIdx.x, t = threadIdx.x;
    int cnt = min(gC[b], BCAP);
    if (t < 128) cnt128[t] = 0;
    __syncthreads();
    for (int i = t; i < cnt; i += 256)
        atomicAdd(&cnt128[tmpC[(size_t)b * BCAP + i] & 127], 1);
    __syncthreads();
    if (t < 128) {
        int n = (b << 7) + t;
        if (n < NN) degi[n] = cnt128[t];
    }
}

// ------- fused edge gather + layer-0 message gather (one CSR pass) -------
__global__ __launch_bounds__(256) void k_fused_edge(const int* __restrict__ rowptr,
        const int* __restrict__ ecol, const float* __restrict__ eat,
        const float* __restrict__ y, const float* __restrict__ A,
        const int* __restrict__ degi, const float* __restrict__ Wne,
        float* __restrict__ nedm, float* __restrict__ xagg0) {
    int t = threadIdx.x, wid = t >> 6, lane = t & 63;
    int n = blockIdx.x * 4 + wid;            // exact: NN/4
    float w0 = (lane < 63) ? Wne[lane] : 0.f;
    int s0 = rowptr[n], s1 = rowptr[n + 1];
    float accn = 0.f, accx = 0.f;
    for (int base = s0; base < s1; base += 64) {
        int m = min(64, s1 - base);
        int cc = (lane < m) ? ecol[base + lane] : 0;
        float aa = (lane < m) ? eat[base + lane] : 0.f;
        int j = 0;
        for (; j + 4 <= m; j += 4) {
            int c0 = __shfl(cc, j), c1 = __shfl(cc, j + 1);
            int c2 = __shfl(cc, j + 2), c3 = __shfl(cc, j + 3);
            float a0 = __shfl(aa, j), a1 = __shfl(aa, j + 1);
            float a2 = __shfl(aa, j + 2), a3 = __shfl(aa, j + 3);
            float y0 = y[(size_t)c0 * DD + lane], y1 = y[(size_t)c1 * DD + lane];
            float y2 = y[(size_t)c2 * DD + lane], y3 = y[(size_t)c3 * DD + lane];
            float v0 = A[(size_t)c0 * DD + lane], v1 = A[(size_t)c1 * DD + lane];
            float v2 = A[(size_t)c2 * DD + lane], v3 = A[(size_t)c3 * DD + lane];
            accn += fmaxf(fmaf(a0, w0, y0), 0.f);
            accn += fmaxf(fmaf(a1, w0, y1), 0.f);
            accn += fmaxf(fmaf(a2, w0, y2), 0.f);
            accn += fmaxf(fmaf(a3, w0, y3), 0.f);
            accx = fmaf(a0, v0, accx); accx = fmaf(a1, v1, accx);
            accx = fmaf(a2, v2, accx); accx = fmaf(a3, v3, accx);
        }
        for (; j < m; ++j) {
            int c = __shfl(cc, j);
            float a = __shfl(aa, j);
            accn += fmaxf(fmaf(a, w0, y[(size_t)c * DD + lane]), 0.f);
            accx = fmaf(a, A[(size_t)c * DD + lane], accx);
        }
    }
    float inv = 1.f / fmaxf((float)(s1 - s0), 1.f);
    nedm[(size_t)n * DD + lane] = (lane < 63) ? accn * inv : (float)degi[n];
    xagg0[(size_t)n * DD + lane] = accx * inv;
}

// ------- fallback (no Y buffer): edge gather only -------
__global__ __launch_bounds__(256) void k_edge_gather(const int* __restrict__ rowptr,
        const int* __restrict__ ecol, const float* __restrict__ eat,
        const float* __restrict__ y, const int* __restrict__ degi,
        const float* __restrict__ Wne, float* __restrict__ nedm) {
    int t = threadIdx.x, wid = t >> 6, lane = t & 63;
    int n = blockIdx.x * 4 + wid;
    float w0 = (lane < 63) ? Wne[lane] : 0.f;
    int s0 = rowptr[n], s1 = rowptr[n + 1];
    float acc = 0.f;
    for (int base = s0; base < s1; base += 64) {
        int m = min(64, s1 - base);
        int cc = (lane < m) ? ecol[base + lane] : 0;
        float aa = (lane < m) ? eat[base + lane] : 0.f;
        for (int j = 0; j < m; ++j) {
            int c = __shfl(cc, j);
            float a = __shfl(aa, j);
            acc += fmaxf(fmaf(a, w0, y[(size_t)c * DD + lane]), 0.f);
        }
    }
    float mean = acc / fmaxf((float)(s1 - s0), 1.f);
    nedm[(size_t)n * DD + lane] = (lane < 63) ? mean : (float)degi[n];
}

// ------- register-blocked GEMM: out = relu(in @ W), K=64; 32 nodes/block -------
__global__ __launch_bounds__(256) void k_gemm64(const float* __restrict__ in,
        const float* __restrict__ W, float* __restrict__ out) {
    __shared__ float sW[DD * DD];
    __shared__ float sI[32][DD];
    int t = threadIdx.x, wid = t >> 6, lane = t & 63;
    int nb = blockIdx.x * 32;        // exact: NN/32 = 3125
    for (int i = t; i < DD * DD / 4; i += 256)
        ((float4*)sW)[i] = ((const float4*)W)[i];
    for (int i = t; i < 32 * DD / 4; i += 256)
        ((float4*)sI)[i] = ((const float4*)(in + (size_t)nb * DD))[i];
    __syncthreads();
    float acc[8] = {0, 0, 0, 0, 0, 0, 0, 0};
    int n0 = wid * 8;
#pragma unroll 4
    for (int kc = 0; kc < 16; ++kc) {
        float w0 = sW[(4 * kc + 0) * DD + lane], w1 = sW[(4 * kc + 1) * DD + lane];
        float w2 = sW[(4 * kc + 2) * DD + lane], w3 = sW[(4 * kc + 3) * DD + lane];
#pragma unroll
        for (int j = 0; j < 8; ++j) {
            float4 v = *(const float4*)&sI[n0 + j][4 * kc];
            acc[j] = fmaf(v.x, w0, acc[j]); acc[j] = fmaf(v.y, w1, acc[j]);
            acc[j] = fmaf(v.z, w2, acc[j]); acc[j] = fmaf(v.w, w3, acc[j]);
        }
    }
#pragma unroll
    for (int j = 0; j < 8; ++j)
        out[(size_t)(nb + n0 + j) * DD + lane] = fmaxf(acc[j], 0.f);
}

// ------- message gather: xagg[n] = mean_e ea * xsrc[col], 8-deep pipeline -------
__global__ __launch_bounds__(256) void k_gather(const int* __restrict__ rowptr,
        const int* __restrict__ ecol, const float* __restrict__ eat,
        const float* __restrict__ xsrc, float* __restrict__ xagg) {
    int t = threadIdx.x, wid = t >> 6, lane = t & 63;
    int n = blockIdx.x * 4 + wid;            // exact: NN/4
    int s0 = rowptr[n], s1 = rowptr[n + 1];
    float acc = 0.f;
    for (int base = s0; base < s1; base += 64) {
        int m = min(64, s1 - base);
        int cc = (lane < m) ? ecol[base + lane] : 0;
        float aa = (lane < m) ? eat[base + lane] : 0.f;
        int j = 0;
        for (; j + 8 <= m; j += 8) {
            int c[8]; float a[8], v[8];
#pragma unroll
            for (int u = 0; u < 8; ++u) { c[u] = __shfl(cc, j + u); a[u] = __shfl(aa, j + u); }
#pragma unroll
            for (int u = 0; u < 8; ++u) v[u] = xsrc[(size_t)c[u] * DD + lane];
#pragma unroll
            for (int u = 0; u < 8; ++u) acc = fmaf(a[u], v[u], acc);
        }
        for (; j < m; ++j) {
            int c = __shfl(cc, j);
            float a = __shfl(aa, j);
            acc = fmaf(a, xsrc[(size_t)c * DD + lane], acc);
        }
    }
    xagg[(size_t)n * DD + lane] = acc / fmaxf((float)(s1 - s0), 1.f);
}

// ------- node update, 4x4 register tile, 64 nodes/block, K split in halves -------
__global__ __launch_bounds__(256) void k_update(const float* __restrict__ xagg,
        const float* __restrict__ C, const float* __restrict__ xsrc,
        const float* __restrict__ Wm, const float* __restrict__ Wu,
        float* __restrict__ xdst) {
    __shared__ __align__(16) float sX[64 * 68];
    __shared__ __align__(16) float sW[64 * 64];
    f32x4* sX4 = (f32x4*)sX;
    f32x4* sW4 = (f32x4*)sW;
    int t = threadIdx.x, tx = t & 15, ty = t >> 4;
    int nb = blockIdx.x * 64;                     // grid NNP/64 = 1563

    auto stageX = [&](const float* __restrict__ src) {
        const f32x4* g = (const f32x4*)src;
        for (int i = t; i < 1024; i += 256) {
            int r = i >> 4, c = i & 15;
            sX4[r * 17 + c] = g[(size_t)(nb + r) * 16 + c];
        }
    };
    auto stageW = [&](const float* __restrict__ w) {
        const f32x4* g = (const f32x4*)w;
        for (int i = t; i < 1024; i += 256) sW4[i] = g[i];
    };
    auto compute = [&](f32x4* acc) {
        const f32x4* x0 = sX4 + (4 * ty + 0) * 17;
        const f32x4* x1 = sX4 + (4 * ty + 1) * 17;
        const f32x4* x2 = sX4 + (4 * ty + 2) * 17;
        const f32x4* x3 = sX4 + (4 * ty + 3) * 17;
#pragma unroll 4
        for (int kc = 0; kc < 16; ++kc) {
            f32x4 a0 = x0[kc], a1 = x1[kc], a2 = x2[kc], a3 = x3[kc];
            f32x4 w0 = sW4[(4 * kc + 0) * 16 + tx];
            f32x4 w1 = sW4[(4 * kc + 1) * 16 + tx];
            f32x4 w2 = sW4[(4 * kc + 2) * 16 + tx];
            f32x4 w3 = sW4[(4 * kc + 3) * 16 + tx];
            acc[0] += a0[0] * w0; acc[0] += a0[1] * w1; acc[0] += a0[2] * w2; acc[0] += a0[3] * w3;
            acc[1] += a1[0] * w0; acc[1] += a1[1] * w1; acc[1] += a1[2] * w2; acc[1] += a1[3] * w3;
            acc[2] += a2[0] * w0; acc[2] += a2[1] * w1; acc[2] += a2[2] * w2; acc[2] += a2[3] * w3;
            acc[3] += a3[0] * w0; acc[3] += a3[1] * w1; acc[3] += a3[2] * w2; acc[3] += a3[3] * w3;
        }
    };

    f32x4 acc1[4] = {}, acc2[4] = {};
    stageX(xagg); stageW(Wm);
    __syncthreads(); compute(acc1); __syncthreads();
    stageX(C); stageW(Wm + 4096);
    __syncthreads(); compute(acc1); __syncthreads();
    f32x4 mm[4];
#pragma unroll
    for (int j = 0; j < 4; ++j) mm[j] = relu4(acc1[j]);
    stageX(xsrc); stageW(Wu);
    __syncthreads(); compute(acc2); __syncthreads();
#pragma unroll
    for (int j = 0; j < 4; ++j) sX4[(4 * ty + j) * 17 + tx] = mm[j];
    stageW(Wu + 4096);
    __syncthreads(); compute(acc2);
    f32x4* gout = (f32x4*)xdst;
#pragma unroll
    for (int j = 0; j < 4; ++j)
        gout[(size_t)(nb + 4 * ty + j) * 16 + tx] = relu4(acc2[j]);
}

// ---------- graph pool / graph GEMM / readout ----------
__global__ __launch_bounds__(256) void k_pool(const float* __restrict__ x_emb,
        const int* __restrict__ batch, float* __restrict__ g_sum,
        float* __restrict__ g_cnt) {
    int gid = blockIdx.x * 256 + threadIdx.x;
    int chunk = gid >> 6, d = gid & 63;
    if (chunk >= NCHUNK) return;
    int n0 = chunk * PCH;
    int curb = batch[n0];
    float s = 0.f, c = 0.f;
    for (int n = n0; n < n0 + PCH; ++n) {
        int b = batch[n];
        if (b != curb) {
            atomicAdd(&g_sum[curb * DD + d], s);
            if (d == 0) atomicAdd(&g_cnt[curb], c);
            s = 0.f; c = 0.f; curb = b;
        }
        s += x_emb[(size_t)n * DD + d];
        c += 1.f;
    }
    atomicAdd(&g_sum[curb * DD + d], s);
    if (d == 0) atomicAdd(&g_cnt[curb], c);
}

__global__ __launch_bounds__(256) void k_graph(const float* __restrict__ g_sum,
        const float* __restrict__ g_cnt, const float* __restrict__ Wg,
        float* __restrict__ g) {
    int gid = blockIdx.x * 256 + threadIdx.x;  // exact: 16 blocks
    int gi = gid >> 6, d = gid & 63;
    float c = fmaxf(g_cnt[gi], 1.f);
    float o = 0.f;
#pragma unroll 8
    for (int k = 0; k < DD; ++k) o += (g_sum[gi * DD + k] / c) * Wg[k * DD + d];
    g[gid] = fmaxf(o, 0.f);
}

__global__ __launch_bounds__(256) void k_readout(const float* __restrict__ x_emb,
        const float* __restrict__ g, const int* __restrict__ batch,
        const float* __restrict__ Wr, const float* __restrict__ br,
        float* __restrict__ q) {
    __shared__ float sWr[2 * DD];
    int t = threadIdx.x;
    if (t < 2 * DD) sWr[t] = Wr[t];
    __syncthreads();
    int n = blockIdx.x * 256 + t;
    if (n >= NN) return;
    int b = batch[n];
    const float* gr = g + b * DD;
    const float* xr = x_emb + (size_t)n * DD;
    float o = br[0];
#pragma unroll 8
    for (int k = 0; k < DD; ++k) o += gr[k] * sWr[k];
#pragma unroll 8
    for (int k = 0; k < DD; ++k) o += xr[k] * sWr[DD + k];
    q[n] = o;
}

extern "C" void kernel_launch(void* const* d_in, const int* in_sizes, int n_in,
                              void* d_out, int out_size, void* d_ws, size_t ws_size,
                              hipStream_t stream) {
    const float* x   = (const float*)d_in[0];
    const int*   ei  = (const int*)d_in[1];
    const float* ea  = (const float*)d_in[2];
    const int*   bat = (const int*)d_in[3];
    const float* Wn  = (const float*)d_in[4];
    const float* Wne = (const float*)d_in[5];
    const float* Wa  = (const float*)d_in[6];
    const float* Wm  = (const float*)d_in[7];
    const float* Wu  = (const float*)d_in[8];
    const float* Wg  = (const float*)d_in[9];
    const float* Wr  = (const float*)d_in[10];
    const float* br  = (const float*)d_in[11];
    float* q = (float*)d_out;

    const size_t FB = (size_t)NNP * DD;
    size_t need4 = (4 * FB + NE + 2 * (size_t)NG * DD + NG) * 4
                 + ((size_t)2 * NN + 1 + NE + 3 * RB + 64) * 4;
    bool fused = ws_size >= need4;

    float* A = (float*)d_ws;                     // x_emb ping
    float* B = A + FB;                           // x_emb pong
    float* C = B + FB;                           // nedm -> x_agg_emb
    float* cur = C + FB;
    float* Y = fused ? cur : B;                  // y buffer (or alias B in fallback)
    if (fused) cur += FB;
    float* eat   = cur;                          // NE
    float* g_sum = eat + NE;                     // NG*DD
    float* g_cnt = g_sum + NG * DD;              // NG
    float* g     = g_cnt + NG;                   // NG*DD
    int* degi    = (int*)(g + NG * DD);          // NN
    int* rowptr  = degi + NN;                    // NN+1
    int* ecol    = rowptr + NN + 1;              // NE
    int* gR      = ecol + NE;                    // RB
    int* gC      = gR + RB;                      // RB
    int* bsR     = gC + RB;                      // RB

    // tmp bucket buffers alias A+B (dead until k_embed_xy)
    uint4* tmpR = (uint4*)A;                          // RB*BCAP*16B = 25.6 MB
    int*   tmpC = (int*)((char*)A + (size_t)RB * BCAP * 16);  // RB*BCAP*4B = 6.4 MB

    hipMemsetAsync(gR, 0, (size_t)2 * RB * sizeof(int), stream);
    hipMemsetAsync(g_sum, 0, (size_t)(NG * DD + NG) * sizeof(float), stream);

    k_bucket<<<B1, 256, 0, stream>>>(ei, ea, gR, gC, tmpR, tmpC);
    k_bscan<<<1, 1024, 0, stream>>>(gR, bsR);
    k_sortbucket<<<RB, 256, 0, stream>>>(gR, bsR, tmpR, rowptr, ecol, eat);
    k_degbucket<<<RB, 256, 0, stream>>>(gC, tmpC, degi);

    k_embed_xy<<<NN * DD / 256, 256, 0, stream>>>(x, Wn, Wne, A, Y);

    if (fused) {
        k_fused_edge<<<NN / 4, 256, 0, stream>>>(rowptr, ecol, eat, Y, A, degi, Wne, C, B);
        k_gemm64<<<NN / 32, 256, 0, stream>>>(C, Wa, C);
    } else {
        k_edge_gather<<<NN / 4, 256, 0, stream>>>(rowptr, ecol, eat, Y, degi, Wne, C);
        k_gemm64<<<NN / 32, 256, 0, stream>>>(C, Wa, C);
        k_gather<<<NN / 4, 256, 0, stream>>>(rowptr, ecol, eat, A, B);  // L0 xagg -> B
    }

    const int UB = NNP / 64;                     // 1563
    k_update<<<UB, 256, 0, stream>>>(B, C, A, Wm, Wu, B);
    k_gather<<<NN / 4, 256, 0, stream>>>(rowptr, ecol, eat, B, A);
    k_update<<<UB, 256, 0, stream>>>(A, C, B, Wm + 8192, Wu + 8192, A);
    k_gather<<<NN / 4, 256, 0, stream>>>(rowptr, ecol, eat, A, B);
    k_update<<<UB, 256, 0, stream>>>(B, C, A, Wm + 16384, Wu + 16384, B);

    k_pool<<<(NCHUNK * DD + 255) / 256, 256, 0, stream>>>(B, bat, g_sum, g_cnt);
    k_graph<<<NG * DD / 256, 256, 0, stream>>>(g_sum, g_cnt, Wg, g);
    k_readout<<<(NN + 255) / 256, 256, 0, stream>>>(B, g, bat, Wr, br, q);
}

// Round 6
// 493.607 us; speedup vs baseline: 3.7805x; 1.1300x over previous
//
#include <hip/hip_runtime.h>

#define NN 100000
#define NNP 100032          // padded to 64-node tiles
#define NE 1200000
#define DIN 7
#define DD 64
#define NL 3
#define NG 64
#define PCH 16
#define NCHUNK (NN / PCH)   // 6250
#define RB 782              // row/col buckets: 99999>>7 = 781
#define BCAP 2048           // per-bucket capacity (mean 1535, std ~39)
#define B1 250              // pass-1 blocks (1024 threads each)
#define CHUNK (NE / B1)     // 4800 exact

typedef float f32x4 __attribute__((ext_vector_type(4)));

__device__ inline f32x4 relu4(f32x4 v) {
    v[0] = fmaxf(v[0], 0.f); v[1] = fmaxf(v[1], 0.f);
    v[2] = fmaxf(v[2], 0.f); v[3] = fmaxf(v[3], 0.f);
    return v;
}
__device__ inline unsigned short f2bf(float f) {        // RNE bf16
    unsigned u = __float_as_uint(f);
    return (unsigned short)((u + 0x7fffu + ((u >> 16) & 1u)) >> 16);
}
__device__ inline float bf2f(unsigned short h) {
    return __uint_as_float(((unsigned)h) << 16);
}

// ------------- fused embed: A = relu(x@Wn) fp32; YAbf[n] = [y bf16 (64) | A bf16 (64)] -------------
// y = x@Wne[1:8,:] (col63=0, no relu). yf (fallback) gets fp32 y if non-null.
__global__ __launch_bounds__(256) void k_embed_xy(const float* __restrict__ x,
        const float* __restrict__ Wn, const float* __restrict__ Wne,
        float* __restrict__ A, unsigned short* __restrict__ yab,
        float* __restrict__ yf) {
    __shared__ float sWn[DIN * DD];
    __shared__ float sWy[DIN * DD];
    int t = threadIdx.x;
    for (int i = t; i < DIN * DD; i += 256) {
        sWn[i] = Wn[i];
        int k = i >> 6, d = i & 63;
        sWy[i] = (d < 63) ? Wne[(k + 1) * 63 + d] : 0.f;
    }
    __syncthreads();
    int gid = blockIdx.x * 256 + t;          // exact grid: NN*DD/256
    int n = gid >> 6, d = gid & 63;
    const float* xr = x + n * DIN;
    float a = 0.f, y = 0.f;
#pragma unroll
    for (int k = 0; k < DIN; ++k) {
        float xv = xr[k];
        a = fmaf(xv, sWn[k * DD + d], a);
        y = fmaf(xv, sWy[k * DD + d], y);
    }
    float ar = fmaxf(a, 0.f);
    A[gid] = ar;
    if (yab) {
        yab[(size_t)n * 128 + d] = f2bf(y);
        yab[(size_t)n * 128 + 64 + d] = f2bf(ar);
    }
    if (yf) yf[gid] = y;
}

// ---------------- CSR build via LDS bucket sort (no scattered global atomics) ----------------
__global__ __launch_bounds__(1024) void k_bucket(const int* __restrict__ ei,
        const float* __restrict__ ea, int* __restrict__ gR, int* __restrict__ gC,
        uint4* __restrict__ tmpR, int* __restrict__ tmpC) {
    __shared__ int hR[RB], hC[RB];
    int t = threadIdx.x;
    for (int i = t; i < RB; i += 1024) { hR[i] = 0; hC[i] = 0; }
    __syncthreads();
    int e0 = blockIdx.x * CHUNK, e1 = e0 + CHUNK;
    for (int e = e0 + t; e < e1; e += 1024) {
        atomicAdd(&hR[ei[e] >> 7], 1);
        atomicAdd(&hC[ei[NE + e] >> 7], 1);
    }
    __syncthreads();
    for (int b = t; b < RB; b += 1024) {
        int n = hR[b]; hR[b] = n ? atomicAdd(&gR[b], n) : 0;
        n = hC[b];     hC[b] = n ? atomicAdd(&gC[b], n) : 0;
    }
    __syncthreads();
    for (int e = e0 + t; e < e1; e += 1024) {
        int r = ei[e], c = ei[NE + e];
        float a = ea[e];
        int br = r >> 7, bc = c >> 7;
        int ir = atomicAdd(&hR[br], 1);
        if (ir < BCAP) tmpR[(size_t)br * BCAP + ir] = make_uint4((unsigned)r, (unsigned)c, __float_as_uint(a), 0u);
        int ic = atomicAdd(&hC[bc], 1);
        if (ic < BCAP) tmpC[(size_t)bc * BCAP + ic] = c;
    }
}

__global__ __launch_bounds__(1024) void k_bscan(const int* __restrict__ gR,
        int* __restrict__ bsR) {
    __shared__ int s[1024];
    int t = threadIdx.x;
    int v = (t < RB) ? gR[t] : 0;
    s[t] = v; __syncthreads();
    for (int off = 1; off < 1024; off <<= 1) {
        int u = (t >= off) ? s[t - off] : 0; __syncthreads();
        s[t] += u; __syncthreads();
    }
    if (t < RB) bsR[t] = s[t] - v;
}

__global__ __launch_bounds__(256) void k_sortbucket(const int* __restrict__ gR,
        const int* __restrict__ bsR, const uint4* __restrict__ tmpR,
        int* __restrict__ rowptr, int* __restrict__ ecol, float* __restrict__ eat) {
    __shared__ uint4 sbuf[BCAP];              // 32 KB
    __shared__ int cnt128[128], off128[128], sscan[128];
    int b = blockIdx.x, t = threadIdx.x;
    int cnt = min(gR[b], BCAP);
    int base = bsR[b];
    if (t < 128) cnt128[t] = 0;
    __syncthreads();
    for (int i = t; i < cnt; i += 256) {
        uint4 rec = tmpR[(size_t)b * BCAP + i];
        sbuf[i] = rec;
        atomicAdd(&cnt128[rec.x & 127], 1);
    }
    __syncthreads();
    if (t < 128) sscan[t] = cnt128[t];
    __syncthreads();
    for (int off = 1; off < 128; off <<= 1) {
        int u = (t < 128 && t >= off) ? sscan[t - off] : 0;
        __syncthreads();
        if (t < 128) sscan[t] += u;
        __syncthreads();
    }
    if (t < 128) {
        int excl = sscan[t] - cnt128[t];
        off128[t] = excl;
        int row = (b << 7) + t;
        if (row <= NN) rowptr[row] = base + excl;
    }
    __syncthreads();
    for (int i = t; i < cnt; i += 256) {
        uint4 rec = sbuf[i];
        int p = atomicAdd(&off128[rec.x & 127], 1);
        ecol[base + p] = (int)rec.y;
        eat[base + p] = __uint_as_float(rec.z);
    }
}

__global__ __launch_bounds__(256) void k_degbucket(const int* __restrict__ gC,
        const int* __restrict__ tmpC, int* __restrict__ degi) {
    __shared__ int cnt128[128];
    int b = blockIdx.x, t = threadIdx.x;
    int cnt = min(gC[b], BCAP);
    if (t < 128) cnt128[t] = 0;
    __syncthreads();
    for (int i = t; i < cnt; i += 256)
        atomicAdd(&cnt128[tmpC[(size_t)b * BCAP + i] & 127], 1);
    __syncthreads();
    if (t < 128) {
        int n = (b << 7) + t;
        if (n < NN) degi[n] = cnt128[t];
    }
}

// ------- fused edge + L0 message gather, bf16 combined rows [y|A] (256 B/edge) -------
__global__ __launch_bounds__(256) void k_fused_edge(const int* __restrict__ rowptr,
        const int* __restrict__ ecol, const float* __restrict__ eat,
        const unsigned short* __restrict__ yab, const int* __restrict__ degi,
        const float* __restrict__ Wne, float* __restrict__ nedm,
        float* __restrict__ xagg0) {
    int t = threadIdx.x, wid = t >> 6, lane = t & 63;
    int n = blockIdx.x * 4 + wid;            // exact: NN/4
    float w0 = (lane < 63) ? Wne[lane] : 0.f;
    int s0 = rowptr[n], s1 = rowptr[n + 1];
    float accn = 0.f, accx = 0.f;
    for (int base = s0; base < s1; base += 64) {
        int m = min(64, s1 - base);
        int cc = (lane < m) ? ecol[base + lane] : 0;
        float aa = (lane < m) ? eat[base + lane] : 0.f;
        int j = 0;
        for (; j + 4 <= m; j += 4) {
            int c0 = __shfl(cc, j), c1 = __shfl(cc, j + 1);
            int c2 = __shfl(cc, j + 2), c3 = __shfl(cc, j + 3);
            float a0 = __shfl(aa, j), a1 = __shfl(aa, j + 1);
            float a2 = __shfl(aa, j + 2), a3 = __shfl(aa, j + 3);
            unsigned short y0 = yab[(size_t)c0 * 128 + lane], y1 = yab[(size_t)c1 * 128 + lane];
            unsigned short y2 = yab[(size_t)c2 * 128 + lane], y3 = yab[(size_t)c3 * 128 + lane];
            unsigned short v0 = yab[(size_t)c0 * 128 + 64 + lane], v1 = yab[(size_t)c1 * 128 + 64 + lane];
            unsigned short v2 = yab[(size_t)c2 * 128 + 64 + lane], v3 = yab[(size_t)c3 * 128 + 64 + lane];
            accn += fmaxf(fmaf(a0, w0, bf2f(y0)), 0.f);
            accn += fmaxf(fmaf(a1, w0, bf2f(y1)), 0.f);
            accn += fmaxf(fmaf(a2, w0, bf2f(y2)), 0.f);
            accn += fmaxf(fmaf(a3, w0, bf2f(y3)), 0.f);
            accx = fmaf(a0, bf2f(v0), accx); accx = fmaf(a1, bf2f(v1), accx);
            accx = fmaf(a2, bf2f(v2), accx); accx = fmaf(a3, bf2f(v3), accx);
        }
        for (; j < m; ++j) {
            int c = __shfl(cc, j);
            float a = __shfl(aa, j);
            accn += fmaxf(fmaf(a, w0, bf2f(yab[(size_t)c * 128 + lane])), 0.f);
            accx = fmaf(a, bf2f(yab[(size_t)c * 128 + 64 + lane]), accx);
        }
    }
    float inv = 1.f / fmaxf((float)(s1 - s0), 1.f);
    nedm[(size_t)n * DD + lane] = (lane < 63) ? accn * inv : (float)degi[n];
    xagg0[(size_t)n * DD + lane] = accx * inv;
}

// ------- fallback (fp32): edge gather only -------
__global__ __launch_bounds__(256) void k_edge_gather(const int* __restrict__ rowptr,
        const int* __restrict__ ecol, const float* __restrict__ eat,
        const float* __restrict__ y, const int* __restrict__ degi,
        const float* __restrict__ Wne, float* __restrict__ nedm) {
    int t = threadIdx.x, wid = t >> 6, lane = t & 63;
    int n = blockIdx.x * 4 + wid;
    float w0 = (lane < 63) ? Wne[lane] : 0.f;
    int s0 = rowptr[n], s1 = rowptr[n + 1];
    float acc = 0.f;
    for (int base = s0; base < s1; base += 64) {
        int m = min(64, s1 - base);
        int cc = (lane < m) ? ecol[base + lane] : 0;
        float aa = (lane < m) ? eat[base + lane] : 0.f;
        for (int j = 0; j < m; ++j) {
            int c = __shfl(cc, j);
            float a = __shfl(aa, j);
            acc += fmaxf(fmaf(a, w0, y[(size_t)c * DD + lane]), 0.f);
        }
    }
    float mean = acc / fmaxf((float)(s1 - s0), 1.f);
    nedm[(size_t)n * DD + lane] = (lane < 63) ? mean : (float)degi[n];
}

// ------- register-blocked GEMM: out = relu(in @ W), K=64; 32 nodes/block -------
__global__ __launch_bounds__(256) void k_gemm64(const float* __restrict__ in,
        const float* __restrict__ W, float* __restrict__ out) {
    __shared__ float sW[DD * DD];
    __shared__ float sI[32][DD];
    int t = threadIdx.x, wid = t >> 6, lane = t & 63;
    int nb = blockIdx.x * 32;        // exact: NN/32 = 3125
    for (int i = t; i < DD * DD / 4; i += 256)
        ((float4*)sW)[i] = ((const float4*)W)[i];
    for (int i = t; i < 32 * DD / 4; i += 256)
        ((float4*)sI)[i] = ((const float4*)(in + (size_t)nb * DD))[i];
    __syncthreads();
    float acc[8] = {0, 0, 0, 0, 0, 0, 0, 0};
    int n0 = wid * 8;
#pragma unroll 4
    for (int kc = 0; kc < 16; ++kc) {
        float w0 = sW[(4 * kc + 0) * DD + lane], w1 = sW[(4 * kc + 1) * DD + lane];
        float w2 = sW[(4 * kc + 2) * DD + lane], w3 = sW[(4 * kc + 3) * DD + lane];
#pragma unroll
        for (int j = 0; j < 8; ++j) {
            float4 v = *(const float4*)&sI[n0 + j][4 * kc];
            acc[j] = fmaf(v.x, w0, acc[j]); acc[j] = fmaf(v.y, w1, acc[j]);
            acc[j] = fmaf(v.z, w2, acc[j]); acc[j] = fmaf(v.w, w3, acc[j]);
        }
    }
#pragma unroll
    for (int j = 0; j < 8; ++j)
        out[(size_t)(nb + n0 + j) * DD + lane] = fmaxf(acc[j], 0.f);
}

// ------- message gather (bf16 src): xagg[n] = mean_e ea * xsrc[col] -------
__global__ __launch_bounds__(256) void k_gather(const int* __restrict__ rowptr,
        const int* __restrict__ ecol, const float* __restrict__ eat,
        const unsigned short* __restrict__ xsrc, float* __restrict__ xagg) {
    int t = threadIdx.x, wid = t >> 6, lane = t & 63;
    int n = blockIdx.x * 4 + wid;            // exact: NN/4
    int s0 = rowptr[n], s1 = rowptr[n + 1];
    float acc = 0.f;
    for (int base = s0; base < s1; base += 64) {
        int m = min(64, s1 - base);
        int cc = (lane < m) ? ecol[base + lane] : 0;
        float aa = (lane < m) ? eat[base + lane] : 0.f;
        int j = 0;
        for (; j + 8 <= m; j += 8) {
            int c[8]; float a[8]; unsigned short v[8];
#pragma unroll
            for (int u = 0; u < 8; ++u) { c[u] = __shfl(cc, j + u); a[u] = __shfl(aa, j + u); }
#pragma unroll
            for (int u = 0; u < 8; ++u) v[u] = xsrc[(size_t)c[u] * DD + lane];
#pragma unroll
            for (int u = 0; u < 8; ++u) acc = fmaf(a[u], bf2f(v[u]), acc);
        }
        for (; j < m; ++j) {
            int c = __shfl(cc, j);
            float a = __shfl(aa, j);
            acc = fmaf(a, bf2f(xsrc[(size_t)c * DD + lane]), acc);
        }
    }
    xagg[(size_t)n * DD + lane] = acc / fmaxf((float)(s1 - s0), 1.f);
}

// ------- fallback fp32 gather -------
__global__ __launch_bounds__(256) void k_gather32(const int* __restrict__ rowptr,
        const int* __restrict__ ecol, const float* __restrict__ eat,
        const float* __restrict__ xsrc, float* __restrict__ xagg) {
    int t = threadIdx.x, wid = t >> 6, lane = t & 63;
    int n = blockIdx.x * 4 + wid;
    int s0 = rowptr[n], s1 = rowptr[n + 1];
    float acc = 0.f;
    for (int base = s0; base < s1; base += 64) {
        int m = min(64, s1 - base);
        int cc = (lane < m) ? ecol[base + lane] : 0;
        float aa = (lane < m) ? eat[base + lane] : 0.f;
        for (int j = 0; j < m; ++j) {
            int c = __shfl(cc, j);
            float a = __shfl(aa, j);
            acc = fmaf(a, xsrc[(size_t)c * DD + lane], acc);
        }
    }
    xagg[(size_t)n * DD + lane] = acc / fmaxf((float)(s1 - s0), 1.f);
}

// ------- node update, 4x4 register tile; optional bf16 mirror of xdst -------
__global__ __launch_bounds__(256) void k_update(const float* __restrict__ xagg,
        const float* __restrict__ C, const float* __restrict__ xsrc,
        const float* __restrict__ Wm, const float* __restrict__ Wu,
        float* __restrict__ xdst, unsigned short* __restrict__ mir) {
    __shared__ __align__(16) float sX[64 * 68];
    __shared__ __align__(16) float sW[64 * 64];
    f32x4* sX4 = (f32x4*)sX;
    f32x4* sW4 = (f32x4*)sW;
    int t = threadIdx.x, tx = t & 15, ty = t >> 4;
    int nb = blockIdx.x * 64;                     // grid NNP/64 = 1563

    auto stageX = [&](const float* __restrict__ src) {
        const f32x4* g = (const f32x4*)src;
        for (int i = t; i < 1024; i += 256) {
            int r = i >> 4, c = i & 15;
            sX4[r * 17 + c] = g[(size_t)(nb + r) * 16 + c];
        }
    };
    auto stageW = [&](const float* __restrict__ w) {
        const f32x4* g = (const f32x4*)w;
        for (int i = t; i < 1024; i += 256) sW4[i] = g[i];
    };
    auto compute = [&](f32x4* acc) {
        const f32x4* x0 = sX4 + (4 * ty + 0) * 17;
        const f32x4* x1 = sX4 + (4 * ty + 1) * 17;
        const f32x4* x2 = sX4 + (4 * ty + 2) * 17;
        const f32x4* x3 = sX4 + (4 * ty + 3) * 17;
#pragma unroll 4
        for (int kc = 0; kc < 16; ++kc) {
            f32x4 a0 = x0[kc], a1 = x1[kc], a2 = x2[kc], a3 = x3[kc];
            f32x4 w0 = sW4[(4 * kc + 0) * 16 + tx];
            f32x4 w1 = sW4[(4 * kc + 1) * 16 + tx];
            f32x4 w2 = sW4[(4 * kc + 2) * 16 + tx];
            f32x4 w3 = sW4[(4 * kc + 3) * 16 + tx];
            acc[0] += a0[0] * w0; acc[0] += a0[1] * w1; acc[0] += a0[2] * w2; acc[0] += a0[3] * w3;
            acc[1] += a1[0] * w0; acc[1] += a1[1] * w1; acc[1] += a1[2] * w2; acc[1] += a1[3] * w3;
            acc[2] += a2[0] * w0; acc[2] += a2[1] * w1; acc[2] += a2[2] * w2; acc[2] += a2[3] * w3;
            acc[3] += a3[0] * w0; acc[3] += a3[1] * w1; acc[3] += a3[2] * w2; acc[3] += a3[3] * w3;
        }
    };

    f32x4 acc1[4] = {}, acc2[4] = {};
    stageX(xagg); stageW(Wm);
    __syncthreads(); compute(acc1); __syncthreads();
    stageX(C); stageW(Wm + 4096);
    __syncthreads(); compute(acc1); __syncthreads();
    f32x4 mm[4];
#pragma unroll
    for (int j = 0; j < 4; ++j) mm[j] = relu4(acc1[j]);
    stageX(xsrc); stageW(Wu);
    __syncthreads(); compute(acc2); __syncthreads();
#pragma unroll
    for (int j = 0; j < 4; ++j) sX4[(4 * ty + j) * 17 + tx] = mm[j];
    stageW(Wu + 4096);
    __syncthreads(); compute(acc2);
    f32x4* gout = (f32x4*)xdst;
#pragma unroll
    for (int j = 0; j < 4; ++j) {
        f32x4 r = relu4(acc2[j]);
        gout[(size_t)(nb + 4 * ty + j) * 16 + tx] = r;
        if (mir) {
            ushort4 mv;
            mv.x = f2bf(r[0]); mv.y = f2bf(r[1]); mv.z = f2bf(r[2]); mv.w = f2bf(r[3]);
            *(ushort4*)&mir[(size_t)(nb + 4 * ty + j) * DD + tx * 4] = mv;
        }
    }
}

// ---------- graph pool / graph GEMM / readout ----------
__global__ __launch_bounds__(256) void k_pool(const float* __restrict__ x_emb,
        const int* __restrict__ batch, float* __restrict__ g_sum,
        float* __restrict__ g_cnt) {
    int gid = blockIdx.x * 256 + threadIdx.x;
    int chunk = gid >> 6, d = gid & 63;
    if (chunk >= NCHUNK) return;
    int n0 = chunk * PCH;
    int curb = batch[n0];
    float s = 0.f, c = 0.f;
    for (int n = n0; n < n0 + PCH; ++n) {
        int b = batch[n];
        if (b != curb) {
            atomicAdd(&g_sum[curb * DD + d], s);
            if (d == 0) atomicAdd(&g_cnt[curb], c);
            s = 0.f; c = 0.f; curb = b;
        }
        s += x_emb[(size_t)n * DD + d];
        c += 1.f;
    }
    atomicAdd(&g_sum[curb * DD + d], s);
    if (d == 0) atomicAdd(&g_cnt[curb], c);
}

__global__ __launch_bounds__(256) void k_graph(const float* __restrict__ g_sum,
        const float* __restrict__ g_cnt, const float* __restrict__ Wg,
        float* __restrict__ g) {
    int gid = blockIdx.x * 256 + threadIdx.x;  // exact: 16 blocks
    int gi = gid >> 6, d = gid & 63;
    float c = fmaxf(g_cnt[gi], 1.f);
    float o = 0.f;
#pragma unroll 8
    for (int k = 0; k < DD; ++k) o += (g_sum[gi * DD + k] / c) * Wg[k * DD + d];
    g[gid] = fmaxf(o, 0.f);
}

__global__ __launch_bounds__(256) void k_readout(const float* __restrict__ x_emb,
        const float* __restrict__ g, const int* __restrict__ batch,
        const float* __restrict__ Wr, const float* __restrict__ br,
        float* __restrict__ q) {
    __shared__ float sWr[2 * DD];
    int t = threadIdx.x;
    if (t < 2 * DD) sWr[t] = Wr[t];
    __syncthreads();
    int n = blockIdx.x * 256 + t;
    if (n >= NN) return;
    int b = batch[n];
    const float* gr = g + b * DD;
    const float* xr = x_emb + (size_t)n * DD;
    float o = br[0];
#pragma unroll 8
    for (int k = 0; k < DD; ++k) o += gr[k] * sWr[k];
#pragma unroll 8
    for (int k = 0; k < DD; ++k) o += xr[k] * sWr[DD + k];
    q[n] = o;
}

extern "C" void kernel_launch(void* const* d_in, const int* in_sizes, int n_in,
                              void* d_out, int out_size, void* d_ws, size_t ws_size,
                              hipStream_t stream) {
    const float* x   = (const float*)d_in[0];
    const int*   ei  = (const int*)d_in[1];
    const float* ea  = (const float*)d_in[2];
    const int*   bat = (const int*)d_in[3];
    const float* Wn  = (const float*)d_in[4];
    const float* Wne = (const float*)d_in[5];
    const float* Wa  = (const float*)d_in[6];
    const float* Wm  = (const float*)d_in[7];
    const float* Wu  = (const float*)d_in[8];
    const float* Wg  = (const float*)d_in[9];
    const float* Wr  = (const float*)d_in[10];
    const float* br  = (const float*)d_in[11];
    float* q = (float*)d_out;

    const size_t FB = (size_t)NNP * DD;
    size_t need4 = (4 * FB + NE + 2 * (size_t)NG * DD + NG) * 4
                 + ((size_t)2 * NN + 1 + NE + 3 * RB + 64) * 4;
    bool fused = ws_size >= need4;

    float* A = (float*)d_ws;                     // x_emb ping (fp32)
    float* B = A + FB;                           // pong
    float* C = B + FB;                           // nedm -> x_agg_emb
    float* cur = C + FB;
    // bf16 region: YAbf [NNP][128] ushort = FB fp32 slots; later reused as Mb|Ma mirrors
    unsigned short* YAbf = fused ? (unsigned short*)cur : nullptr;
    unsigned short* Mb = YAbf;                   // mirror of L0 out (first half)
    unsigned short* Ma = YAbf ? YAbf + (size_t)NNP * DD : nullptr;  // mirror of L1 out
    float* Yf = fused ? nullptr : B;             // fp32 y fallback aliases B
    if (fused) cur += FB;
    float* eat   = cur;                          // NE
    float* g_sum = eat + NE;                     // NG*DD
    float* g_cnt = g_sum + NG * DD;              // NG
    float* g     = g_cnt + NG;                   // NG*DD
    int* degi    = (int*)(g + NG * DD);          // NN
    int* rowptr  = degi + NN;                    // NN+1
    int* ecol    = rowptr + NN + 1;              // NE
    int* gR      = ecol + NE;                    // RB
    int* gC      = gR + RB;                      // RB
    int* bsR     = gC + RB;                      // RB

    // tmp bucket buffers alias A+B (dead until k_embed_xy)
    uint4* tmpR = (uint4*)A;                          // RB*BCAP*16B = 25.6 MB
    int*   tmpC = (int*)((char*)A + (size_t)RB * BCAP * 16);  // 6.4 MB

    hipMemsetAsync(gR, 0, (size_t)2 * RB * sizeof(int), stream);
    hipMemsetAsync(g_sum, 0, (size_t)(NG * DD + NG) * sizeof(float), stream);

    k_bucket<<<B1, 1024, 0, stream>>>(ei, ea, gR, gC, tmpR, tmpC);
    k_bscan<<<1, 1024, 0, stream>>>(gR, bsR);
    k_sortbucket<<<RB, 256, 0, stream>>>(gR, bsR, tmpR, rowptr, ecol, eat);
    k_degbucket<<<RB, 256, 0, stream>>>(gC, tmpC, degi);

    k_embed_xy<<<NN * DD / 256, 256, 0, stream>>>(x, Wn, Wne, A, YAbf, Yf);

    const int UB = NNP / 64;                     // 1563
    if (fused) {
        // one CSR pass over [y|A] bf16: nedm -> C, L0 xagg -> B
        k_fused_edge<<<NN / 4, 256, 0, stream>>>(rowptr, ecol, eat, YAbf, degi, Wne, C, B);
        k_gemm64<<<NN / 32, 256, 0, stream>>>(C, Wa, C);
        // L0: xagg=B, xsrc=A -> B (+ mirror Mb overwrites dead y-half of YAbf)
        k_update<<<UB, 256, 0, stream>>>(B, C, A, Wm, Wu, B, Mb);
        k_gather<<<NN / 4, 256, 0, stream>>>(rowptr, ecol, eat, Mb, A);
        k_update<<<UB, 256, 0, stream>>>(A, C, B, Wm + 8192, Wu + 8192, A, Ma);
        k_gather<<<NN / 4, 256, 0, stream>>>(rowptr, ecol, eat, Ma, B);
        k_update<<<UB, 256, 0, stream>>>(B, C, A, Wm + 16384, Wu + 16384, B, nullptr);
    } else {
        // fp32 fallback path
        k_edge_gather<<<NN / 4, 256, 0, stream>>>(rowptr, ecol, eat, Yf, degi, Wne, C);
        k_gemm64<<<NN / 32, 256, 0, stream>>>(C, Wa, C);
        k_gather32<<<NN / 4, 256, 0, stream>>>(rowptr, ecol, eat, A, B);
        k_update<<<UB, 256, 0, stream>>>(B, C, A, Wm, Wu, B, nullptr);
        k_gather32<<<NN / 4, 256, 0, stream>>>(rowptr, ecol, eat, B, A);
        k_update<<<UB, 256, 0, stream>>>(A, C, B, Wm + 8192, Wu + 8192, A, nullptr);
        k_gather32<<<NN / 4, 256, 0, stream>>>(rowptr, ecol, eat, A, B);
        k_update<<<UB, 256, 0, stream>>>(B, C, A, Wm + 16384, Wu + 16384, B, nullptr);
    }

    k_pool<<<(NCHUNK * DD + 255) / 256, 256, 0, stream>>>(B, bat, g_sum, g_cnt);
    k_graph<<<NG * DD / 256, 256, 0, stream>>>(g_sum, g_cnt, Wg, g);
    k_readout<<<(NN + 255) / 256, 256, 0, stream>>>(B, g, bat, Wr, br, q);
}